// Round 1
// baseline (624.678 us; speedup 1.0000x reference)
//
#include <hip/hip_runtime.h>
#include <stdint.h>

#define DEVI __device__ __forceinline__

typedef __bf16 bf16x8 __attribute__((ext_vector_type(8)));
typedef float  f32x4  __attribute__((ext_vector_type(4)));
typedef unsigned int u32x2 __attribute__((ext_vector_type(2)));
typedef unsigned int u32x4 __attribute__((ext_vector_type(4)));

// B=4, N=4096, DIM=1024, H=16, D=64, M=128, DIM_INNER=1024, SCALE=0.125

DEVI unsigned short f2bf(float f) {  // RNE f32->bf16
  union { float f; unsigned int u; } c; c.f = f;
  return (unsigned short)((c.u + 0x7fffu + ((c.u >> 16) & 1u)) >> 16);
}
DEVI float bf2f(unsigned short s) {
  union { unsigned int u; float f; } c; c.u = ((unsigned int)s) << 16;
  return c.f;
}
DEVI bf16x8 ldg8(const unsigned short* p) { return *(const bf16x8*)p; }

DEVI void g2l16(const void* g, void* l) {
  __builtin_amdgcn_global_load_lds(
      (const __attribute__((address_space(1))) unsigned int*)g,
      (__attribute__((address_space(3))) unsigned int*)l, 16, 0, 0);
}

#define MFMA16(acc, a, b) acc = __builtin_amdgcn_mfma_f32_16x16x32_bf16((a), (b), (acc), 0, 0, 0)

// ---------------- prep: fp32->bf16 conversions (+transposes, +agent scale) ------------
__global__ __launch_bounds__(256) void k_prep(
    const float* __restrict__ x, const float* __restrict__ Wqkv,
    const float* __restrict__ ag, const float* __restrict__ Wout,
    unsigned short* __restrict__ Xb, unsigned short* __restrict__ WqkvT,
    unsigned short* __restrict__ Ab, unsigned short* __restrict__ WoT)
{
  size_t idx = (size_t)blockIdx.x * 256 + threadIdx.x;
  if (idx < 16777216) { Xb[idx] = f2bf(x[idx]); return; }
  idx -= 16777216;
  if (idx < 3145728) {           // WqkvT[j][k] = Wqkv[k][j]
    unsigned j = (unsigned)(idx >> 10), k = (unsigned)(idx & 1023);
    WqkvT[idx] = f2bf(Wqkv[(size_t)k * 3072 + j]); return;
  }
  idx -= 3145728;
  if (idx < 131072) { Ab[idx] = f2bf(ag[idx] * 0.125f); return; }  // a = agent*SCALE
  idx -= 131072;
  if (idx < 1048576) {           // WoT[c][d] = Wout[d][c]
    unsigned c = (unsigned)(idx >> 10), d = (unsigned)(idx & 1023);
    WoT[idx] = f2bf(Wout[(size_t)d * 1024 + c]);
  }
}

// ---------------- GEMM1: C[16384,3072] = Xb @ WqkvT^T ; scatter to Q,K,Vt -------------
// m97 recipe: 128x128 tile, BK=32, 4 waves 2x2, global_load_lds width 16.
__global__ __launch_bounds__(256, 2) void k_gemm_qkv(
    const unsigned short* __restrict__ A, const unsigned short* __restrict__ Bt,
    unsigned short* __restrict__ Q, unsigned short* __restrict__ Kd,
    unsigned short* __restrict__ Vt)
{
  __shared__ __align__(16) unsigned short lA[4096];
  __shared__ __align__(16) unsigned short lB[4096];
  const int tid = threadIdx.x, lane = tid & 63, w = tid >> 6;
  const int q = lane >> 4, r = lane & 15, wr = w >> 1, wc = w & 1;
  const int row0 = blockIdx.y * 128, col0 = blockIdx.x * 128;
  const int c1 = w, c2 = w + 4;
  const int sr1 = c1 * 16 + (lane >> 2), sr2 = c2 * 16 + (lane >> 2);
  const int sk = 8 * (lane & 3);
  const unsigned short* gA1 = A + (size_t)(row0 + sr1) * 1024 + sk;
  const unsigned short* gA2 = A + (size_t)(row0 + sr2) * 1024 + sk;
  const unsigned short* gB1 = Bt + (size_t)(col0 + sr1) * 1024 + sk;
  const unsigned short* gB2 = Bt + (size_t)(col0 + sr2) * 1024 + sk;
  f32x4 acc[4][4];
  const f32x4 z = {0.f, 0.f, 0.f, 0.f};
#pragma unroll
  for (int i = 0; i < 4; i++)
#pragma unroll
    for (int j = 0; j < 4; j++) acc[i][j] = z;

  for (int k0 = 0; k0 < 1024; k0 += 32) {
    g2l16(gA1 + k0, &lA[c1 * 512]);
    g2l16(gA2 + k0, &lA[c2 * 512]);
    g2l16(gB1 + k0, &lB[c1 * 512]);
    g2l16(gB2 + k0, &lB[c2 * 512]);
    __syncthreads();
    bf16x8 af[4], bv[4];
#pragma unroll
    for (int rt = 0; rt < 4; rt++) af[rt] = *(const bf16x8*)&lA[(64 * wr + 16 * rt + r) * 32 + q * 8];
#pragma unroll
    for (int ct = 0; ct < 4; ct++) bv[ct] = *(const bf16x8*)&lB[(64 * wc + 16 * ct + r) * 32 + q * 8];
#pragma unroll
    for (int rt = 0; rt < 4; rt++)
#pragma unroll
      for (int ct = 0; ct < 4; ct++) MFMA16(acc[rt][ct], af[rt], bv[ct]);
    __syncthreads();
  }
  // epilogue: col sections 128-aligned => whole block is Q (bx<8), K (bx<16) or V
  const int b = row0 >> 12;
  if (blockIdx.x < 16) {
    unsigned short* dst = (blockIdx.x < 8) ? Q : Kd;
#pragma unroll
    for (int rt = 0; rt < 4; rt++)
#pragma unroll
      for (int ct = 0; ct < 4; ct++) {
        int j = (col0 & 1023) + 64 * wc + 16 * ct + r;
        int h = j >> 6, d = j & 63;
#pragma unroll
        for (int reg = 0; reg < 4; reg++) {
          int n = (row0 & 4095) + 64 * wr + 16 * rt + 4 * q + reg;
          dst[(((size_t)(b * 16 + h)) * 4096 + n) * 64 + d] = f2bf(acc[rt][ct][reg]);
        }
      }
  } else {  // V -> transposed store Vt[b,h,d,n]; pack 4 consecutive n (regs) as 8B
#pragma unroll
    for (int rt = 0; rt < 4; rt++)
#pragma unroll
      for (int ct = 0; ct < 4; ct++) {
        int j = (col0 - 2048) + 64 * wc + 16 * ct + r;
        int h = j >> 6, d = j & 63;
        int nb = (row0 & 4095) + 64 * wr + 16 * rt + 4 * q;
        unsigned short v0 = f2bf(acc[rt][ct][0]), v1 = f2bf(acc[rt][ct][1]);
        unsigned short v2 = f2bf(acc[rt][ct][2]), v3 = f2bf(acc[rt][ct][3]);
        u32x2 pk = {(unsigned)v0 | ((unsigned)v1 << 16), (unsigned)v2 | ((unsigned)v3 << 16)};
        *(u32x2*)&Vt[(((size_t)(b * 16 + h)) * 64 + d) * 4096 + nb] = pk;
      }
  }
}

// ---------------- qa: sim = Q@a^T, softmax over m, write QA[b,n,h,m] bf16 -------------
__global__ __launch_bounds__(256, 2) void k_qa(
    const unsigned short* __restrict__ Q, const unsigned short* __restrict__ Ab,
    unsigned short* __restrict__ QA)
{
  const int tid = threadIdx.x, lane = tid & 63, w = tid >> 6;
  const int q = lane >> 4, r = lane & 15, wr = w >> 1, wc = w & 1;
  const int nt = blockIdx.x, h = blockIdx.y, b = blockIdx.z;
  const unsigned short* Qb = Q + (((size_t)(b * 16 + h)) * 4096 + nt * 128) * 64;
  const unsigned short* Ah = Ab + (size_t)h * 8192;
  f32x4 acc[4][4];
  const f32x4 z = {0.f, 0.f, 0.f, 0.f};
#pragma unroll
  for (int i = 0; i < 4; i++)
#pragma unroll
    for (int j = 0; j < 4; j++) acc[i][j] = z;
#pragma unroll
  for (int ks = 0; ks < 2; ks++) {
    bf16x8 af[4], bv[4];
#pragma unroll
    for (int rt = 0; rt < 4; rt++) af[rt] = ldg8(Qb + (size_t)(64 * wr + 16 * rt + r) * 64 + ks * 32 + q * 8);
#pragma unroll
    for (int ct = 0; ct < 4; ct++) bv[ct] = ldg8(Ah + (size_t)(64 * wc + 16 * ct + r) * 64 + ks * 32 + q * 8);
#pragma unroll
    for (int rt = 0; rt < 4; rt++)
#pragma unroll
      for (int ct = 0; ct < 4; ct++) MFMA16(acc[rt][ct], af[rt], bv[ct]);
  }
  // softmax over cols (m). |sim|<~0.2 so no max-subtraction needed.
  __shared__ float rs[2][128];
  float sp[4][4];
#pragma unroll
  for (int rt = 0; rt < 4; rt++)
#pragma unroll
    for (int reg = 0; reg < 4; reg++) {
      float s = 0.f;
#pragma unroll
      for (int ct = 0; ct < 4; ct++) {
        float e = __expf(acc[rt][ct][reg]);
        acc[rt][ct][reg] = e; s += e;
      }
      s += __shfl_xor(s, 1); s += __shfl_xor(s, 2); s += __shfl_xor(s, 4); s += __shfl_xor(s, 8);
      sp[rt][reg] = s;
    }
  if (r == 0) {
#pragma unroll
    for (int rt = 0; rt < 4; rt++)
#pragma unroll
      for (int reg = 0; reg < 4; reg++) rs[wc][64 * wr + 16 * rt + 4 * q + reg] = sp[rt][reg];
  }
  __syncthreads();
#pragma unroll
  for (int rt = 0; rt < 4; rt++)
#pragma unroll
    for (int reg = 0; reg < 4; reg++) {
      int row = 64 * wr + 16 * rt + 4 * q + reg;
      float inv = 1.0f / (rs[0][row] + rs[1][row]);
      int n = nt * 128 + row;
      size_t base = (((size_t)(b * 4096 + n)) * 16 + h) * 128 + 64 * wc;
#pragma unroll
      for (int ct = 0; ct < 4; ct++) QA[base + 16 * ct + r] = f2bf(acc[rt][ct][reg] * inv);
    }
}

// ------- ak: sim = a@K^T, mask, exp; write E[b,h,m,n] bf16 + atomic row sums ----------
__global__ __launch_bounds__(256, 2) void k_ak(
    const unsigned short* __restrict__ Kd, const unsigned short* __restrict__ Ab,
    const int* __restrict__ mask, unsigned short* __restrict__ E, float* __restrict__ rowsum)
{
  const int tid = threadIdx.x, lane = tid & 63, w = tid >> 6;
  const int q = lane >> 4, r = lane & 15, wr = w >> 1, wc = w & 1;
  const int nt = blockIdx.x, h = blockIdx.y, b = blockIdx.z;
  const unsigned short* Kb = Kd + (((size_t)(b * 16 + h)) * 4096 + nt * 128) * 64;
  const unsigned short* Ah = Ab + (size_t)h * 8192;
  f32x4 acc[4][4];
  const f32x4 z = {0.f, 0.f, 0.f, 0.f};
#pragma unroll
  for (int i = 0; i < 4; i++)
#pragma unroll
    for (int j = 0; j < 4; j++) acc[i][j] = z;
#pragma unroll
  for (int ks = 0; ks < 2; ks++) {
    bf16x8 af[4], bv[4];
#pragma unroll
    for (int rt = 0; rt < 4; rt++) af[rt] = ldg8(Ah + (size_t)(64 * wr + 16 * rt + r) * 64 + ks * 32 + q * 8);
#pragma unroll
    for (int ct = 0; ct < 4; ct++) bv[ct] = ldg8(Kb + (size_t)(64 * wc + 16 * ct + r) * 64 + ks * 32 + q * 8);
#pragma unroll
    for (int rt = 0; rt < 4; rt++)
#pragma unroll
      for (int ct = 0; ct < 4; ct++) MFMA16(acc[rt][ct], af[rt], bv[ct]);
  }
  int mk[4];
#pragma unroll
  for (int ct = 0; ct < 4; ct++) mk[ct] = mask[b * 4096 + nt * 128 + 64 * wc + 16 * ct + r];
  __shared__ float rs[2][128];
  float sp[4][4];
#pragma unroll
  for (int rt = 0; rt < 4; rt++)
#pragma unroll
    for (int reg = 0; reg < 4; reg++) {
      float s = 0.f;
#pragma unroll
      for (int ct = 0; ct < 4; ct++) {
        float e = mk[ct] ? __expf(acc[rt][ct][reg]) : 0.0f;
        acc[rt][ct][reg] = e; s += e;
      }
      s += __shfl_xor(s, 1); s += __shfl_xor(s, 2); s += __shfl_xor(s, 4); s += __shfl_xor(s, 8);
      sp[rt][reg] = s;
    }
  if (r == 0) {
#pragma unroll
    for (int rt = 0; rt < 4; rt++)
#pragma unroll
      for (int reg = 0; reg < 4; reg++) rs[wc][64 * wr + 16 * rt + 4 * q + reg] = sp[rt][reg];
  }
#pragma unroll
  for (int rt = 0; rt < 4; rt++)
#pragma unroll
    for (int ct = 0; ct < 4; ct++)
#pragma unroll
      for (int reg = 0; reg < 4; reg++) {
        int m = 64 * wr + 16 * rt + 4 * q + reg;
        int n = nt * 128 + 64 * wc + 16 * ct + r;
        E[(((size_t)(b * 16 + h)) * 128 + m) * 4096 + n] = f2bf(acc[rt][ct][reg]);
      }
  __syncthreads();
  if (wc == 0 && r == 0) {
#pragma unroll
    for (int rt = 0; rt < 4; rt++)
#pragma unroll
      for (int reg = 0; reg < 4; reg++) {
        int row = 64 * wr + 16 * rt + 4 * q + reg;
        atomicAdd(&rowsum[(b * 16 + h) * 128 + row], rs[0][row] + rs[1][row]);
      }
  }
}

// ---------- mix: MIX[b,g,m,n] = sum_h Wak[g,h] * E[b,h,m,n]/rowsum[b,h,m] -------------
__global__ __launch_bounds__(256) void k_mix(
    const unsigned short* __restrict__ E, const float* __restrict__ rowsum,
    const float* __restrict__ Wak, unsigned short* __restrict__ MIX)
{
  const int tid = threadIdx.x;
  const int nt = blockIdx.x, m = blockIdx.y, b = blockIdx.z;
  __shared__ float w[256];
  __shared__ float inv[16];
  w[tid] = Wak[tid];
  if (tid < 16) inv[tid] = 1.0f / rowsum[(b * 16 + tid) * 128 + m];
  __syncthreads();
  for (int ii = 0; ii < 2; ii++) {
    int n = nt * 512 + ii * 256 + tid;
    float p[16];
#pragma unroll
    for (int h = 0; h < 16; h++)
      p[h] = bf2f(E[(((size_t)(b * 16 + h)) * 128 + m) * 4096 + n]) * inv[h];
#pragma unroll
    for (int g = 0; g < 16; g++) {
      float s = 0.f;
#pragma unroll
      for (int h = 0; h < 16; h++) s += w[g * 16 + h] * p[h];
      MIX[(((size_t)(b * 16 + g)) * 128 + m) * 4096 + n] = f2bf(s);
    }
  }
}

// ---------------- AO[b,g,128,64] = MIX[b,g] @ V[b,g]  (K=4096, k-split + atomics) -----
__global__ __launch_bounds__(256) void k_ao(
    const unsigned short* __restrict__ MIX, const unsigned short* __restrict__ Vt,
    float* __restrict__ AO)
{
  const int tid = threadIdx.x, lane = tid & 63, w4 = tid >> 6;
  const int q = lane >> 4, r = lane & 15;
  const int kc = blockIdx.x, g = blockIdx.y, b = blockIdx.z;
  const unsigned short* Abase = MIX + ((size_t)(b * 16 + g)) * 128 * 4096;
  const unsigned short* Bbase = Vt + ((size_t)(b * 16 + g)) * 64 * 4096;
  f32x4 acc[2][4];
  const f32x4 z = {0.f, 0.f, 0.f, 0.f};
#pragma unroll
  for (int i = 0; i < 2; i++)
#pragma unroll
    for (int j = 0; j < 4; j++) acc[i][j] = z;
  for (int n = kc * 1024; n < kc * 1024 + 1024; n += 32) {
    bf16x8 af[2], bv[4];
#pragma unroll
    for (int rt = 0; rt < 2; rt++) af[rt] = ldg8(Abase + (size_t)(32 * w4 + 16 * rt + r) * 4096 + n + q * 8);
#pragma unroll
    for (int ct = 0; ct < 4; ct++) bv[ct] = ldg8(Bbase + (size_t)(16 * ct + r) * 4096 + n + q * 8);
#pragma unroll
    for (int rt = 0; rt < 2; rt++)
#pragma unroll
      for (int ct = 0; ct < 4; ct++) MFMA16(acc[rt][ct], af[rt], bv[ct]);
  }
#pragma unroll
  for (int rt = 0; rt < 2; rt++)
#pragma unroll
    for (int ct = 0; ct < 4; ct++)
#pragma unroll
      for (int reg = 0; reg < 4; reg++) {
        int m = 32 * w4 + 16 * rt + 4 * q + reg, d = 16 * ct + r;
        atomicAdd(&AO[(((size_t)(b * 16 + g)) * 128 + m) * 64 + d], acc[rt][ct][reg]);
      }
}

// ---------------- U[b,g,128,1024] = AO[b,g] @ Wout[g*64:(g+1)*64, :] ------------------
__global__ __launch_bounds__(256, 2) void k_u(
    const float* __restrict__ AO, const unsigned short* __restrict__ WoT,
    float* __restrict__ U)
{
  const int tid = threadIdx.x, lane = tid & 63, w = tid >> 6;
  const int q = lane >> 4, r = lane & 15, wr = w >> 1, wc = w & 1;
  const int ctile = blockIdx.x, g = blockIdx.y, b = blockIdx.z;
  const float* Abase = AO + ((size_t)(b * 16 + g)) * 128 * 64;
  const unsigned short* Bbase = WoT + (size_t)(ctile * 128) * 1024 + g * 64;
  f32x4 acc[4][4];
  const f32x4 z = {0.f, 0.f, 0.f, 0.f};
#pragma unroll
  for (int i = 0; i < 4; i++)
#pragma unroll
    for (int j = 0; j < 4; j++) acc[i][j] = z;
#pragma unroll
  for (int ks = 0; ks < 2; ks++) {
    bf16x8 af[4], bv[4];
#pragma unroll
    for (int rt = 0; rt < 4; rt++) {
      const float* p = Abase + (size_t)(64 * wr + 16 * rt + r) * 64 + ks * 32 + q * 8;
      f32x4 f0 = *(const f32x4*)p;
      f32x4 f1 = *(const f32x4*)(p + 4);
      bf16x8 t;
#pragma unroll
      for (int jj = 0; jj < 4; jj++) { t[jj] = (__bf16)f0[jj]; t[4 + jj] = (__bf16)f1[jj]; }
      af[rt] = t;
    }
#pragma unroll
    for (int ct = 0; ct < 4; ct++) bv[ct] = ldg8(Bbase + (size_t)(64 * wc + 16 * ct + r) * 1024 + ks * 32 + q * 8);
#pragma unroll
    for (int rt = 0; rt < 4; rt++)
#pragma unroll
      for (int ct = 0; ct < 4; ct++) MFMA16(acc[rt][ct], af[rt], bv[ct]);
  }
#pragma unroll
  for (int rt = 0; rt < 4; rt++)
#pragma unroll
    for (int ct = 0; ct < 4; ct++)
#pragma unroll
      for (int reg = 0; reg < 4; reg++) {
        int m = 64 * wr + 16 * rt + 4 * q + reg;
        int c = ctile * 128 + 64 * wc + 16 * ct + r;
        U[(((size_t)(b * 16 + g)) * 128 + m) * 1024 + c] = acc[rt][ct][reg];
      }
}

// ---------------- Tt[b,c,h*128+m] = sum_g Wqa[g,h] * U[b,g,m,c] -----------------------
__global__ __launch_bounds__(256) void k_t(
    const float* __restrict__ U, const float* __restrict__ Wqa,
    unsigned short* __restrict__ Tt)
{
  const int tid = threadIdx.x;
  const int cc = blockIdx.x, h = blockIdx.y, b = blockIdx.z;
  const int c = cc * 256 + tid;
  __shared__ float w[16];
  if (tid < 16) w[tid] = Wqa[(size_t)tid * 16 + h];
  __syncthreads();
  unsigned short* dst = Tt + ((size_t)(b * 1024 + c)) * 2048 + h * 128;
  const float* Ub = U + (size_t)b * 16 * 128 * 1024 + c;
  unsigned int pk[4];
  for (int m = 0; m < 128; m++) {
    float s = 0.f;
#pragma unroll
    for (int g = 0; g < 16; g++) s += w[g] * Ub[((size_t)g * 128 + m) * 1024];
    unsigned short v = f2bf(s);
    int sl = m & 7;
    if (sl & 1) pk[sl >> 1] |= ((unsigned)v << 16); else pk[sl >> 1] = v;
    if (sl == 7) {
      u32x4 vv = {pk[0], pk[1], pk[2], pk[3]};
      *(u32x4*)(dst + m - 7) = vv;
    }
  }
}

// ------- GEMM6: out[b] = QA[b][4096,2048] @ Tt[b][1024,2048]^T, mask rows, fp32 -------
__global__ __launch_bounds__(256, 2) void k_final(
    const unsigned short* __restrict__ QAg, const unsigned short* __restrict__ Ttg,
    const int* __restrict__ mask, float* __restrict__ out)
{
  __shared__ __align__(16) unsigned short lA[4096];
  __shared__ __align__(16) unsigned short lB[4096];
  const int tid = threadIdx.x, lane = tid & 63, w = tid >> 6;
  const int q = lane >> 4, r = lane & 15, wr = w >> 1, wc = w & 1;
  const int row0 = blockIdx.y * 128, col0 = blockIdx.x * 128, b = blockIdx.z;
  const unsigned short* A = QAg + (size_t)b * 4096 * 2048;
  const unsigned short* Bt = Ttg + (size_t)b * 1024 * 2048;
  const int c1 = w, c2 = w + 4;
  const int sr1 = c1 * 16 + (lane >> 2), sr2 = c2 * 16 + (lane >> 2);
  const int sk = 8 * (lane & 3);
  const unsigned short* gA1 = A + (size_t)(row0 + sr1) * 2048 + sk;
  const unsigned short* gA2 = A + (size_t)(row0 + sr2) * 2048 + sk;
  const unsigned short* gB1 = Bt + (size_t)(col0 + sr1) * 2048 + sk;
  const unsigned short* gB2 = Bt + (size_t)(col0 + sr2) * 2048 + sk;
  f32x4 acc[4][4];
  const f32x4 z = {0.f, 0.f, 0.f, 0.f};
#pragma unroll
  for (int i = 0; i < 4; i++)
#pragma unroll
    for (int j = 0; j < 4; j++) acc[i][j] = z;
  for (int k0 = 0; k0 < 2048; k0 += 32) {
    g2l16(gA1 + k0, &lA[c1 * 512]);
    g2l16(gA2 + k0, &lA[c2 * 512]);
    g2l16(gB1 + k0, &lB[c1 * 512]);
    g2l16(gB2 + k0, &lB[c2 * 512]);
    __syncthreads();
    bf16x8 af[4], bv[4];
#pragma unroll
    for (int rt = 0; rt < 4; rt++) af[rt] = *(const bf16x8*)&lA[(64 * wr + 16 * rt + r) * 32 + q * 8];
#pragma unroll
    for (int ct = 0; ct < 4; ct++) bv[ct] = *(const bf16x8*)&lB[(64 * wc + 16 * ct + r) * 32 + q * 8];
#pragma unroll
    for (int rt = 0; rt < 4; rt++)
#pragma unroll
      for (int ct = 0; ct < 4; ct++) MFMA16(acc[rt][ct], af[rt], bv[ct]);
    __syncthreads();
  }
#pragma unroll
  for (int rt = 0; rt < 4; rt++)
#pragma unroll
    for (int reg = 0; reg < 4; reg++) {
      int n = row0 + 64 * wr + 16 * rt + 4 * q + reg;
      int mv = mask[b * 4096 + n];
#pragma unroll
      for (int ct = 0; ct < 4; ct++) {
        int c = col0 + 64 * wc + 16 * ct + r;
        out[((size_t)b * 4096 + n) * 1024 + c] = mv ? acc[rt][ct][reg] : 0.0f;
      }
    }
}

// =====================================================================================
extern "C" void kernel_launch(void* const* d_in, const int* in_sizes, int n_in,
                              void* d_out, int out_size, void* d_ws, size_t ws_size,
                              hipStream_t stream) {
  const float* x    = (const float*)d_in[0];
  const int*   mask = (const int*)d_in[1];       // bool -> int32 per harness rule
  const float* Wqkv = (const float*)d_in[2];
  const float* ag   = (const float*)d_in[3];
  const float* Wqa  = (const float*)d_in[4];
  const float* Wak  = (const float*)d_in[5];
  const float* Wout = (const float*)d_in[6];
  float* out = (float*)d_out;
  char* ws = (char*)d_ws;

  // workspace layout (lifetime-overlapped), total 239,370,240 B (~228 MiB)
  unsigned short* QA    = (unsigned short*)(ws + 0);          // 67.1 MB  [k_qa -> k_final]
  unsigned short* VT    = (unsigned short*)(ws + 67108864);   // 33.5 MB  Vt [gemm1 -> k_ao]; Tt after
  unsigned short* QQ    = (unsigned short*)(ws + 100663296);  // 33.5 MB  Q  [gemm1 -> k_qa]
  unsigned short* KK    = (unsigned short*)(ws + 134217728);  // 33.5 MB  K  [gemm1 -> k_ak]
  unsigned short* MIXED = QQ;                                 // 67.1 MB spans QQ+KK [k_mix -> k_ao]
  unsigned short* Xb    = (unsigned short*)(ws + 167772160);  // 33.5 MB  [prep -> gemm1]
  unsigned short* WqkvT = (unsigned short*)(ws + 167772160 + 33554432); // 6.3 MB
  unsigned short* E     = Xb;                                 // 67.1 MB region reuse [k_ak -> k_mix]
  char* sm = ws + 234881024;
  unsigned short* Ab  = (unsigned short*)(sm);                // 256 KB agent tokens (scaled, bf16)
  unsigned short* WoT = (unsigned short*)(sm + 262144);       // 2 MB  Wout^T bf16
  float* rowsum = (float*)(sm + 262144 + 2097152);            // 32 KB
  float* AO     = (float*)(sm + 262144 + 2097152 + 32768);    // 2 MB
  float* U      = (float*)QQ;                                 // 33.5 MB [k_u -> k_t] (MIX dead)
  unsigned short* Tt = VT;                                    // 16.8 MB [k_t -> k_final] (Vt dead)

  hipMemsetAsync(rowsum, 0, 4 * 16 * 128 * 4, stream);
  hipMemsetAsync(AO, 0, 4 * 16 * 128 * 64 * 4, stream);

  k_prep<<<82432, 256, 0, stream>>>(x, Wqkv, ag, Wout, Xb, WqkvT, Ab, WoT);
  k_gemm_qkv<<<dim3(24, 128), 256, 0, stream>>>(Xb, WqkvT, QQ, KK, VT);
  k_qa<<<dim3(32, 16, 4), 256, 0, stream>>>(QQ, Ab, QA);
  k_ak<<<dim3(32, 16, 4), 256, 0, stream>>>(KK, Ab, mask, E, rowsum);
  k_mix<<<dim3(8, 128, 4), 256, 0, stream>>>(E, rowsum, Wak, MIXED);
  k_ao<<<dim3(4, 16, 4), 256, 0, stream>>>(MIXED, VT, AO);
  k_u<<<dim3(8, 16, 4), 256, 0, stream>>>(AO, WoT, U);
  k_t<<<dim3(4, 16, 4), 256, 0, stream>>>(U, Wqa, Tt);
  k_final<<<dim3(8, 32, 4), 256, 0, stream>>>(QA, Tt, mask, out);
}

// Round 2
// 578.611 us; speedup vs baseline: 1.0796x; 1.0796x over previous
//
#include <hip/hip_runtime.h>
#include <stdint.h>

#define DEVI __device__ __forceinline__

typedef __bf16 bf16x8 __attribute__((ext_vector_type(8)));
typedef float  f32x4  __attribute__((ext_vector_type(4)));
typedef unsigned int u32x2 __attribute__((ext_vector_type(2)));
typedef unsigned int u32x4 __attribute__((ext_vector_type(4)));

// B=4, N=4096, DIM=1024, H=16, D=64, M=128, DIM_INNER=1024, SCALE=0.125

DEVI unsigned short f2bf(float f) {  // RNE f32->bf16
  union { float f; unsigned int u; } c; c.f = f;
  return (unsigned short)((c.u + 0x7fffu + ((c.u >> 16) & 1u)) >> 16);
}
DEVI float bf2f(unsigned short s) {
  union { unsigned int u; float f; } c; c.u = ((unsigned int)s) << 16;
  return c.f;
}
DEVI bf16x8 ldg8(const unsigned short* p) { return *(const bf16x8*)p; }

DEVI void g2l16(const void* g, void* l) {
  __builtin_amdgcn_global_load_lds(
      (const __attribute__((address_space(1))) unsigned int*)g,
      (__attribute__((address_space(3))) unsigned int*)l, 16, 0, 0);
}

#define MFMA16(acc, a, b) acc = __builtin_amdgcn_mfma_f32_16x16x32_bf16((a), (b), (acc), 0, 0, 0)

// ---------------- prep: fp32->bf16 conversions (+transposes, +agent scale) ------------
__global__ __launch_bounds__(256) void k_prep(
    const float* __restrict__ x, const float* __restrict__ Wqkv,
    const float* __restrict__ ag, const float* __restrict__ Wout,
    unsigned short* __restrict__ Xb, unsigned short* __restrict__ WqkvT,
    unsigned short* __restrict__ Ab, unsigned short* __restrict__ WoT)
{
  size_t idx = (size_t)blockIdx.x * 256 + threadIdx.x;
  if (idx < 16777216) { Xb[idx] = f2bf(x[idx]); return; }
  idx -= 16777216;
  if (idx < 3145728) {           // WqkvT[j][k] = Wqkv[k][j]
    unsigned j = (unsigned)(idx >> 10), k = (unsigned)(idx & 1023);
    WqkvT[idx] = f2bf(Wqkv[(size_t)k * 3072 + j]); return;
  }
  idx -= 3145728;
  if (idx < 131072) { Ab[idx] = f2bf(ag[idx] * 0.125f); return; }  // a = agent*SCALE
  idx -= 131072;
  if (idx < 1048576) {           // WoT[c][d] = Wout[d][c]
    unsigned c = (unsigned)(idx >> 10), d = (unsigned)(idx & 1023);
    WoT[idx] = f2bf(Wout[(size_t)d * 1024 + c]);
  }
}

// ---------------- GEMM1: C[16384,3072] = Xb @ WqkvT^T ; scatter to Q,K,Vt -------------
__global__ __launch_bounds__(256, 2) void k_gemm_qkv(
    const unsigned short* __restrict__ A, const unsigned short* __restrict__ Bt,
    unsigned short* __restrict__ Q, unsigned short* __restrict__ Kd,
    unsigned short* __restrict__ Vt)
{
  __shared__ __align__(16) unsigned short lA[4096];
  __shared__ __align__(16) unsigned short lB[4096];
  const int tid = threadIdx.x, lane = tid & 63, w = tid >> 6;
  const int q = lane >> 4, r = lane & 15, wr = w >> 1, wc = w & 1;
  const int row0 = blockIdx.y * 128, col0 = blockIdx.x * 128;
  const int c1 = w, c2 = w + 4;
  const int sr1 = c1 * 16 + (lane >> 2), sr2 = c2 * 16 + (lane >> 2);
  const int sk = 8 * (lane & 3);
  const unsigned short* gA1 = A + (size_t)(row0 + sr1) * 1024 + sk;
  const unsigned short* gA2 = A + (size_t)(row0 + sr2) * 1024 + sk;
  const unsigned short* gB1 = Bt + (size_t)(col0 + sr1) * 1024 + sk;
  const unsigned short* gB2 = Bt + (size_t)(col0 + sr2) * 1024 + sk;
  f32x4 acc[4][4];
  const f32x4 z = {0.f, 0.f, 0.f, 0.f};
#pragma unroll
  for (int i = 0; i < 4; i++)
#pragma unroll
    for (int j = 0; j < 4; j++) acc[i][j] = z;

  for (int k0 = 0; k0 < 1024; k0 += 32) {
    g2l16(gA1 + k0, &lA[c1 * 512]);
    g2l16(gA2 + k0, &lA[c2 * 512]);
    g2l16(gB1 + k0, &lB[c1 * 512]);
    g2l16(gB2 + k0, &lB[c2 * 512]);
    __syncthreads();
    bf16x8 af[4], bv[4];
#pragma unroll
    for (int rt = 0; rt < 4; rt++) af[rt] = *(const bf16x8*)&lA[(64 * wr + 16 * rt + r) * 32 + q * 8];
#pragma unroll
    for (int ct = 0; ct < 4; ct++) bv[ct] = *(const bf16x8*)&lB[(64 * wc + 16 * ct + r) * 32 + q * 8];
#pragma unroll
    for (int rt = 0; rt < 4; rt++)
#pragma unroll
      for (int ct = 0; ct < 4; ct++) MFMA16(acc[rt][ct], af[rt], bv[ct]);
    __syncthreads();
  }
  // epilogue: col sections 128-aligned => whole block is Q (bx<8), K (bx<16) or V
  const int b = row0 >> 12;
  if (blockIdx.x < 16) {
    unsigned short* dst = (blockIdx.x < 8) ? Q : Kd;
#pragma unroll
    for (int rt = 0; rt < 4; rt++)
#pragma unroll
      for (int ct = 0; ct < 4; ct++) {
        int j = (col0 & 1023) + 64 * wc + 16 * ct + r;
        int h = j >> 6, d = j & 63;
#pragma unroll
        for (int reg = 0; reg < 4; reg++) {
          int n = (row0 & 4095) + 64 * wr + 16 * rt + 4 * q + reg;
          dst[(((size_t)(b * 16 + h)) * 4096 + n) * 64 + d] = f2bf(acc[rt][ct][reg]);
        }
      }
  } else {  // V -> transposed store Vt[b,h,d,n]; pack 4 consecutive n (regs) as 8B
#pragma unroll
    for (int rt = 0; rt < 4; rt++)
#pragma unroll
      for (int ct = 0; ct < 4; ct++) {
        int j = (col0 - 2048) + 64 * wc + 16 * ct + r;
        int h = j >> 6, d = j & 63;
        int nb = (row0 & 4095) + 64 * wr + 16 * rt + 4 * q;
        unsigned short v0 = f2bf(acc[rt][ct][0]), v1 = f2bf(acc[rt][ct][1]);
        unsigned short v2 = f2bf(acc[rt][ct][2]), v3 = f2bf(acc[rt][ct][3]);
        u32x2 pk = {(unsigned)v0 | ((unsigned)v1 << 16), (unsigned)v2 | ((unsigned)v3 << 16)};
        *(u32x2*)&Vt[(((size_t)(b * 16 + h)) * 64 + d) * 4096 + nb] = pk;
      }
  }
}

// ---------------- qa: sim = Q@a^T, softmax over m, write QA[b,h,n,m] bf16 -------------
__global__ __launch_bounds__(256, 2) void k_qa(
    const unsigned short* __restrict__ Q, const unsigned short* __restrict__ Ab,
    unsigned short* __restrict__ QA)
{
  const int tid = threadIdx.x, lane = tid & 63, w = tid >> 6;
  const int q = lane >> 4, r = lane & 15, wr = w >> 1, wc = w & 1;
  const int nt = blockIdx.x, h = blockIdx.y, b = blockIdx.z;
  const unsigned short* Qb = Q + (((size_t)(b * 16 + h)) * 4096 + nt * 128) * 64;
  const unsigned short* Ah = Ab + (size_t)h * 8192;
  f32x4 acc[4][4];
  const f32x4 z = {0.f, 0.f, 0.f, 0.f};
#pragma unroll
  for (int i = 0; i < 4; i++)
#pragma unroll
    for (int j = 0; j < 4; j++) acc[i][j] = z;
#pragma unroll
  for (int ks = 0; ks < 2; ks++) {
    bf16x8 af[4], bv[4];
#pragma unroll
    for (int rt = 0; rt < 4; rt++) af[rt] = ldg8(Qb + (size_t)(64 * wr + 16 * rt + r) * 64 + ks * 32 + q * 8);
#pragma unroll
    for (int ct = 0; ct < 4; ct++) bv[ct] = ldg8(Ah + (size_t)(64 * wc + 16 * ct + r) * 64 + ks * 32 + q * 8);
#pragma unroll
    for (int rt = 0; rt < 4; rt++)
#pragma unroll
      for (int ct = 0; ct < 4; ct++) MFMA16(acc[rt][ct], af[rt], bv[ct]);
  }
  // softmax over cols (m). |sim|<~0.2 so no max-subtraction needed.
  __shared__ float rs[2][128];
  float sp[4][4];
#pragma unroll
  for (int rt = 0; rt < 4; rt++)
#pragma unroll
    for (int reg = 0; reg < 4; reg++) {
      float s = 0.f;
#pragma unroll
      for (int ct = 0; ct < 4; ct++) {
        float e = __expf(acc[rt][ct][reg]);
        acc[rt][ct][reg] = e; s += e;
      }
      s += __shfl_xor(s, 1); s += __shfl_xor(s, 2); s += __shfl_xor(s, 4); s += __shfl_xor(s, 8);
      sp[rt][reg] = s;
    }
  if (r == 0) {
#pragma unroll
    for (int rt = 0; rt < 4; rt++)
#pragma unroll
      for (int reg = 0; reg < 4; reg++) rs[wc][64 * wr + 16 * rt + 4 * q + reg] = sp[rt][reg];
  }
  __syncthreads();
#pragma unroll
  for (int rt = 0; rt < 4; rt++)
#pragma unroll
    for (int reg = 0; reg < 4; reg++) {
      int row = 64 * wr + 16 * rt + 4 * q + reg;
      float inv = 1.0f / (rs[0][row] + rs[1][row]);
      int n = nt * 128 + row;
      size_t base = (((size_t)(b * 16 + h)) * 4096 + n) * 128 + 64 * wc;
#pragma unroll
      for (int ct = 0; ct < 4; ct++) QA[base + 16 * ct + r] = f2bf(acc[rt][ct][reg] * inv);
    }
}

// ------- ak: sim = a@K^T, mask, exp; write E[b,h,m,n] bf16 + atomic row sums ----------
__global__ __launch_bounds__(256, 2) void k_ak(
    const unsigned short* __restrict__ Kd, const unsigned short* __restrict__ Ab,
    const int* __restrict__ mask, unsigned short* __restrict__ E, float* __restrict__ rowsum)
{
  const int tid = threadIdx.x, lane = tid & 63, w = tid >> 6;
  const int q = lane >> 4, r = lane & 15, wr = w >> 1, wc = w & 1;
  const int nt = blockIdx.x, h = blockIdx.y, b = blockIdx.z;
  const unsigned short* Kb = Kd + (((size_t)(b * 16 + h)) * 4096 + nt * 128) * 64;
  const unsigned short* Ah = Ab + (size_t)h * 8192;
  f32x4 acc[4][4];
  const f32x4 z = {0.f, 0.f, 0.f, 0.f};
#pragma unroll
  for (int i = 0; i < 4; i++)
#pragma unroll
    for (int j = 0; j < 4; j++) acc[i][j] = z;
#pragma unroll
  for (int ks = 0; ks < 2; ks++) {
    bf16x8 af[4], bv[4];
#pragma unroll
    for (int rt = 0; rt < 4; rt++) af[rt] = ldg8(Ah + (size_t)(64 * wr + 16 * rt + r) * 64 + ks * 32 + q * 8);
#pragma unroll
    for (int ct = 0; ct < 4; ct++) bv[ct] = ldg8(Kb + (size_t)(64 * wc + 16 * ct + r) * 64 + ks * 32 + q * 8);
#pragma unroll
    for (int rt = 0; rt < 4; rt++)
#pragma unroll
      for (int ct = 0; ct < 4; ct++) MFMA16(acc[rt][ct], af[rt], bv[ct]);
  }
  int mk[4];
#pragma unroll
  for (int ct = 0; ct < 4; ct++) mk[ct] = mask[b * 4096 + nt * 128 + 64 * wc + 16 * ct + r];
  __shared__ float rs[2][128];
  float sp[4][4];
#pragma unroll
  for (int rt = 0; rt < 4; rt++)
#pragma unroll
    for (int reg = 0; reg < 4; reg++) {
      float s = 0.f;
#pragma unroll
      for (int ct = 0; ct < 4; ct++) {
        float e = mk[ct] ? __expf(acc[rt][ct][reg]) : 0.0f;
        acc[rt][ct][reg] = e; s += e;
      }
      s += __shfl_xor(s, 1); s += __shfl_xor(s, 2); s += __shfl_xor(s, 4); s += __shfl_xor(s, 8);
      sp[rt][reg] = s;
    }
  if (r == 0) {
#pragma unroll
    for (int rt = 0; rt < 4; rt++)
#pragma unroll
      for (int reg = 0; reg < 4; reg++) rs[wc][64 * wr + 16 * rt + 4 * q + reg] = sp[rt][reg];
  }
#pragma unroll
  for (int rt = 0; rt < 4; rt++)
#pragma unroll
    for (int ct = 0; ct < 4; ct++)
#pragma unroll
      for (int reg = 0; reg < 4; reg++) {
        int m = 64 * wr + 16 * rt + 4 * q + reg;
        int n = nt * 128 + 64 * wc + 16 * ct + r;
        E[(((size_t)(b * 16 + h)) * 128 + m) * 4096 + n] = f2bf(acc[rt][ct][reg]);
      }
  __syncthreads();
  if (wc == 0 && r == 0) {
#pragma unroll
    for (int rt = 0; rt < 4; rt++)
#pragma unroll
      for (int reg = 0; reg < 4; reg++) {
        int row = 64 * wr + 16 * rt + 4 * q + reg;
        atomicAdd(&rowsum[(b * 16 + h) * 128 + row], rs[0][row] + rs[1][row]);
      }
  }
}

// ---------- mix: MIX[b,g,m,n] = sum_h Wak[g,h] * E[b,h,m,n]/rowsum[b,h,m] -------------
__global__ __launch_bounds__(256) void k_mix(
    const unsigned short* __restrict__ E, const float* __restrict__ rowsum,
    const float* __restrict__ Wak, unsigned short* __restrict__ MIX)
{
  const int tid = threadIdx.x;
  const int nt = blockIdx.x, m = blockIdx.y, b = blockIdx.z;
  __shared__ float w[256];
  __shared__ float inv[16];
  w[tid] = Wak[tid];
  if (tid < 16) inv[tid] = 1.0f / rowsum[(b * 16 + tid) * 128 + m];
  __syncthreads();
  for (int ii = 0; ii < 2; ii++) {
    int n = nt * 512 + ii * 256 + tid;
    float p[16];
#pragma unroll
    for (int h = 0; h < 16; h++)
      p[h] = bf2f(E[(((size_t)(b * 16 + h)) * 128 + m) * 4096 + n]) * inv[h];
#pragma unroll
    for (int g = 0; g < 16; g++) {
      float s = 0.f;
#pragma unroll
      for (int h = 0; h < 16; h++) s += w[g * 16 + h] * p[h];
      MIX[(((size_t)(b * 16 + g)) * 128 + m) * 4096 + n] = f2bf(s);
    }
  }
}

// ---------------- AO[b,g,128,64] = MIX[b,g] @ V[b,g]  (K=4096, k-split x8 + atomics) --
__global__ __launch_bounds__(256) void k_ao(
    const unsigned short* __restrict__ MIX, const unsigned short* __restrict__ Vt,
    float* __restrict__ AO)
{
  const int tid = threadIdx.x, lane = tid & 63, w4 = tid >> 6;
  const int q = lane >> 4, r = lane & 15;
  const int kc = blockIdx.x, g = blockIdx.y, b = blockIdx.z;
  const unsigned short* Abase = MIX + ((size_t)(b * 16 + g)) * 128 * 4096;
  const unsigned short* Bbase = Vt + ((size_t)(b * 16 + g)) * 64 * 4096;
  f32x4 acc[2][4];
  const f32x4 z = {0.f, 0.f, 0.f, 0.f};
#pragma unroll
  for (int i = 0; i < 2; i++)
#pragma unroll
    for (int j = 0; j < 4; j++) acc[i][j] = z;
  for (int n = kc * 512; n < kc * 512 + 512; n += 32) {
    bf16x8 af[2], bv[4];
#pragma unroll
    for (int rt = 0; rt < 2; rt++) af[rt] = ldg8(Abase + (size_t)(32 * w4 + 16 * rt + r) * 4096 + n + q * 8);
#pragma unroll
    for (int ct = 0; ct < 4; ct++) bv[ct] = ldg8(Bbase + (size_t)(16 * ct + r) * 4096 + n + q * 8);
#pragma unroll
    for (int rt = 0; rt < 2; rt++)
#pragma unroll
      for (int ct = 0; ct < 4; ct++) MFMA16(acc[rt][ct], af[rt], bv[ct]);
  }
#pragma unroll
  for (int rt = 0; rt < 2; rt++)
#pragma unroll
    for (int ct = 0; ct < 4; ct++)
#pragma unroll
      for (int reg = 0; reg < 4; reg++) {
        int m = 32 * w4 + 16 * rt + 4 * q + reg, d = 16 * ct + r;
        atomicAdd(&AO[(((size_t)(b * 16 + g)) * 128 + m) * 64 + d], acc[rt][ct][reg]);
      }
}

// ---------------- aocvt: AObT[b,g,d,m] = bf16(AO[b,g,m,d]) ---------------------------
__global__ __launch_bounds__(256) void k_aocvt(
    const float* __restrict__ AO, unsigned short* __restrict__ AObT)
{
  unsigned idx = blockIdx.x * 256 + threadIdx.x;   // 524288 total
  unsigned m = idx & 127, rest = idx >> 7;
  unsigned d = rest & 63; rest >>= 6;
  AObT[idx] = f2bf(AO[((size_t)rest * 128 + m) * 64 + d]);
}

// ---------- mixqa: QAmix[b,g,n,m] = sum_h Wqa[g,h] * QA[b,h,n,m] ---------------------
__global__ __launch_bounds__(256) void k_mixqa(
    const unsigned short* __restrict__ QA, const float* __restrict__ Wqa,
    unsigned short* __restrict__ QAmix)
{
  const int tid = threadIdx.x;
  const int blk = blockIdx.x, b = blockIdx.y;
  __shared__ float w[256];
  w[tid] = Wqa[tid];
  __syncthreads();
  for (int ii = 0; ii < 2; ii++) {
    unsigned idx = (unsigned)blk * 512 + ii * 256 + tid;  // over n*128+m plane (524288)
    float p[16];
#pragma unroll
    for (int h = 0; h < 16; h++)
      p[h] = bf2f(QA[((size_t)(b * 16 + h)) * 524288 + idx]);
#pragma unroll
    for (int g = 0; g < 16; g++) {
      float s = 0.f;
#pragma unroll
      for (int h = 0; h < 16; h++) s += w[g * 16 + h] * p[h];
      QAmix[((size_t)(b * 16 + g)) * 524288 + idx] = f2bf(s);
    }
  }
}

// ---------- o1: out1[b,n,g*64+d] = QAmix[b,g,n,:] @ AObT[b,g,d,:]  (K=128) -----------
__global__ __launch_bounds__(256) void k_o1(
    const unsigned short* __restrict__ QAmix, const unsigned short* __restrict__ AObT,
    unsigned short* __restrict__ out1)
{
  const int tid = threadIdx.x, lane = tid & 63, w4 = tid >> 6;
  const int q = lane >> 4, r = lane & 15;
  const int nt = blockIdx.x, g = blockIdx.y, b = blockIdx.z;
  const unsigned short* Abase = QAmix + (((size_t)(b * 16 + g)) * 4096 + nt * 128) * 128;
  const unsigned short* Bbase = AObT + ((size_t)(b * 16 + g)) * 64 * 128;
  f32x4 acc[2][4];
  const f32x4 z = {0.f, 0.f, 0.f, 0.f};
#pragma unroll
  for (int i = 0; i < 2; i++)
#pragma unroll
    for (int j = 0; j < 4; j++) acc[i][j] = z;
#pragma unroll
  for (int ks = 0; ks < 4; ks++) {
    bf16x8 af[2], bv[4];
#pragma unroll
    for (int rt = 0; rt < 2; rt++) af[rt] = ldg8(Abase + (size_t)(32 * w4 + 16 * rt + r) * 128 + ks * 32 + q * 8);
#pragma unroll
    for (int ct = 0; ct < 4; ct++) bv[ct] = ldg8(Bbase + (size_t)(16 * ct + r) * 128 + ks * 32 + q * 8);
#pragma unroll
    for (int rt = 0; rt < 2; rt++)
#pragma unroll
      for (int ct = 0; ct < 4; ct++) MFMA16(acc[rt][ct], af[rt], bv[ct]);
  }
#pragma unroll
  for (int rt = 0; rt < 2; rt++)
#pragma unroll
    for (int reg = 0; reg < 4; reg++) {
      int n = nt * 128 + 32 * w4 + 16 * rt + 4 * q + reg;
      size_t base = ((size_t)b * 4096 + n) * 1024 + g * 64;
#pragma unroll
      for (int ct = 0; ct < 4; ct++) out1[base + 16 * ct + r] = f2bf(acc[rt][ct][reg]);
    }
}

// ------- fin2: out[16384,1024] = out1[16384,1024] @ WoT^T, mask rows, fp32 -----------
__global__ __launch_bounds__(256, 2) void k_fin2(
    const unsigned short* __restrict__ A, const unsigned short* __restrict__ Bt,
    const int* __restrict__ mask, float* __restrict__ out)
{
  __shared__ __align__(16) unsigned short lA[4096];
  __shared__ __align__(16) unsigned short lB[4096];
  const int tid = threadIdx.x, lane = tid & 63, w = tid >> 6;
  const int q = lane >> 4, r = lane & 15, wr = w >> 1, wc = w & 1;
  const int row0 = blockIdx.y * 128, col0 = blockIdx.x * 128;
  const int c1 = w, c2 = w + 4;
  const int sr1 = c1 * 16 + (lane >> 2), sr2 = c2 * 16 + (lane >> 2);
  const int sk = 8 * (lane & 3);
  const unsigned short* gA1 = A + (size_t)(row0 + sr1) * 1024 + sk;
  const unsigned short* gA2 = A + (size_t)(row0 + sr2) * 1024 + sk;
  const unsigned short* gB1 = Bt + (size_t)(col0 + sr1) * 1024 + sk;
  const unsigned short* gB2 = Bt + (size_t)(col0 + sr2) * 1024 + sk;
  f32x4 acc[4][4];
  const f32x4 z = {0.f, 0.f, 0.f, 0.f};
#pragma unroll
  for (int i = 0; i < 4; i++)
#pragma unroll
    for (int j = 0; j < 4; j++) acc[i][j] = z;
  for (int k0 = 0; k0 < 1024; k0 += 32) {
    g2l16(gA1 + k0, &lA[c1 * 512]);
    g2l16(gA2 + k0, &lA[c2 * 512]);
    g2l16(gB1 + k0, &lB[c1 * 512]);
    g2l16(gB2 + k0, &lB[c2 * 512]);
    __syncthreads();
    bf16x8 af[4], bv[4];
#pragma unroll
    for (int rt = 0; rt < 4; rt++) af[rt] = *(const bf16x8*)&lA[(64 * wr + 16 * rt + r) * 32 + q * 8];
#pragma unroll
    for (int ct = 0; ct < 4; ct++) bv[ct] = *(const bf16x8*)&lB[(64 * wc + 16 * ct + r) * 32 + q * 8];
#pragma unroll
    for (int rt = 0; rt < 4; rt++)
#pragma unroll
      for (int ct = 0; ct < 4; ct++) MFMA16(acc[rt][ct], af[rt], bv[ct]);
    __syncthreads();
  }
#pragma unroll
  for (int rt = 0; rt < 4; rt++)
#pragma unroll
    for (int reg = 0; reg < 4; reg++) {
      int row = row0 + 64 * wr + 16 * rt + 4 * q + reg;
      int mv = mask[row];
#pragma unroll
      for (int ct = 0; ct < 4; ct++) {
        int c = col0 + 64 * wc + 16 * ct + r;
        out[(size_t)row * 1024 + c] = mv ? acc[rt][ct][reg] : 0.0f;
      }
    }
}

// =====================================================================================
extern "C" void kernel_launch(void* const* d_in, const int* in_sizes, int n_in,
                              void* d_out, int out_size, void* d_ws, size_t ws_size,
                              hipStream_t stream) {
  const float* x    = (const float*)d_in[0];
  const int*   mask = (const int*)d_in[1];       // bool -> int32 per harness rule
  const float* Wqkv = (const float*)d_in[2];
  const float* ag   = (const float*)d_in[3];
  const float* Wqa  = (const float*)d_in[4];
  const float* Wak  = (const float*)d_in[5];
  const float* Wout = (const float*)d_in[6];
  float* out = (float*)d_out;
  char* ws = (char*)d_ws;

  // workspace layout, lifetime-overlapped; total 239,370,240 B (same as round 1)
  // R1 [0,64Mi):        QA                [k_qa -> k_mixqa]
  // R2 [64Mi,128Mi):    QQ|KK             [gemm -> qa/ak], MIX [mix -> ao], out1 [o1 -> fin2]
  // R3 [128Mi,160Mi):   VT                [gemm -> ao], AObT [aocvt -> o1]
  // R4 [160Mi,224Mi):   Xb+WqkvT          [prep -> gemm], E [ak -> mix], QAmix [mixqa -> o1]
  unsigned short* QA    = (unsigned short*)(ws + 0);
  unsigned short* QQ    = (unsigned short*)(ws + 67108864);
  unsigned short* KK    = (unsigned short*)(ws + 67108864 + 33554432);
  unsigned short* MIX   = QQ;
  unsigned short* out1  = QQ;
  unsigned short* VT    = (unsigned short*)(ws + 134217728);
  unsigned short* AObT  = VT;
  unsigned short* Xb    = (unsigned short*)(ws + 167772160);
  unsigned short* WqkvT = (unsigned short*)(ws + 167772160 + 33554432);
  unsigned short* E     = Xb;
  unsigned short* QAmix = Xb;
  char* sm = ws + 234881024;
  unsigned short* Ab  = (unsigned short*)(sm);                 // 256 KB
  unsigned short* WoT = (unsigned short*)(sm + 262144);        // 2 MB
  float* rowsum = (float*)(sm + 262144 + 2097152);             // 32 KB
  float* AO     = (float*)(sm + 262144 + 2097152 + 32768);     // 2 MB

  hipMemsetAsync(rowsum, 0, 4 * 16 * 128 * 4, stream);
  hipMemsetAsync(AO, 0, 4 * 16 * 128 * 64 * 4, stream);

  k_prep<<<82432, 256, 0, stream>>>(x, Wqkv, ag, Wout, Xb, WqkvT, Ab, WoT);
  k_gemm_qkv<<<dim3(24, 128), 256, 0, stream>>>(Xb, WqkvT, QQ, KK, VT);
  k_qa<<<dim3(32, 16, 4), 256, 0, stream>>>(QQ, Ab, QA);
  k_ak<<<dim3(32, 16, 4), 256, 0, stream>>>(KK, Ab, mask, E, rowsum);
  k_mix<<<dim3(8, 128, 4), 256, 0, stream>>>(E, rowsum, Wak, MIX);
  k_ao<<<dim3(8, 16, 4), 256, 0, stream>>>(MIX, VT, AO);
  k_aocvt<<<2048, 256, 0, stream>>>(AO, AObT);
  k_mixqa<<<dim3(1024, 4), 256, 0, stream>>>(QA, Wqa, QAmix);
  k_o1<<<dim3(32, 16, 4), 256, 0, stream>>>(QAmix, AObT, out1);
  k_fin2<<<dim3(8, 128), 256, 0, stream>>>(out1, WoT, mask, out);
}

// Round 3
// 547.221 us; speedup vs baseline: 1.1415x; 1.0574x over previous
//
#include <hip/hip_runtime.h>
#include <stdint.h>

#define DEVI __device__ __forceinline__

typedef __bf16 bf16x8 __attribute__((ext_vector_type(8)));
typedef float  f32x4  __attribute__((ext_vector_type(4)));
typedef unsigned int u32x2 __attribute__((ext_vector_type(2)));
typedef unsigned int u32x4 __attribute__((ext_vector_type(4)));

// B=4, N=4096, DIM=1024, H=16, D=64, M=128, DIM_INNER=1024, SCALE=0.125

DEVI unsigned short f2bf(float f) {  // RNE f32->bf16
  union { float f; unsigned int u; } c; c.f = f;
  return (unsigned short)((c.u + 0x7fffu + ((c.u >> 16) & 1u)) >> 16);
}
DEVI float bf2f(unsigned short s) {
  union { unsigned int u; float f; } c; c.u = ((unsigned int)s) << 16;
  return c.f;
}
DEVI u32x2 pack4(float a, float b, float c, float d) {
  u32x2 r;
  r.x = (unsigned)f2bf(a) | ((unsigned)f2bf(b) << 16);
  r.y = (unsigned)f2bf(c) | ((unsigned)f2bf(d) << 16);
  return r;
}
DEVI bf16x8 ldg8(const unsigned short* p) { return *(const bf16x8*)p; }

DEVI void g2l16(const void* g, void* l) {
  __builtin_amdgcn_global_load_lds(
      (const __attribute__((address_space(1))) unsigned int*)g,
      (__attribute__((address_space(3))) unsigned int*)l, 16, 0, 0);
}

#define MFMA16(acc, a, b) acc = __builtin_amdgcn_mfma_f32_16x16x32_bf16((a), (b), (acc), 0, 0, 0)

// ---------------- prep: fp32->bf16 cvt (vectorized) + LDS-tiled transposes ------------
// blocks [0,16384): x cvt (4/thread) | [16384,19456): Wqkv^T | [19456,19584): agent*SCALE
// | [19584,20608): Wout^T
__global__ __launch_bounds__(256) void k_prep(
    const float* __restrict__ x, const float* __restrict__ Wqkv,
    const float* __restrict__ ag, const float* __restrict__ Wout,
    unsigned short* __restrict__ Xb, unsigned short* __restrict__ WqkvT,
    unsigned short* __restrict__ Ab, unsigned short* __restrict__ WoT)
{
  __shared__ float ldsT[32][33];
  const int tid = threadIdx.x;
  int bx = blockIdx.x;
  if (bx < 16384) {                     // x: 16.7M elems, 4/thread
    size_t i4 = ((size_t)bx * 256 + tid) * 4;
    f32x4 v = *(const f32x4*)&x[i4];
    *(u32x2*)&Xb[i4] = pack4(v[0], v[1], v[2], v[3]);
    return;
  }
  bx -= 16384;
  if (bx < 3072) {                      // WqkvT[j][k] = Wqkv[k][j], 32x32 tiles
    int jt = bx % 96, kt = bx / 96;
    int r32 = tid >> 3, c4 = (tid & 7) * 4;
    f32x4 v = *(const f32x4*)&Wqkv[(size_t)(kt * 32 + r32) * 3072 + jt * 32 + c4];
#pragma unroll
    for (int i = 0; i < 4; i++) ldsT[r32][c4 + i] = v[i];
    __syncthreads();
    float o0 = ldsT[c4 + 0][r32], o1 = ldsT[c4 + 1][r32];
    float o2 = ldsT[c4 + 2][r32], o3 = ldsT[c4 + 3][r32];
    *(u32x2*)&WqkvT[(size_t)(jt * 32 + r32) * 1024 + kt * 32 + c4] = pack4(o0, o1, o2, o3);
    return;
  }
  bx -= 3072;
  if (bx < 128) {                       // agent tokens * SCALE
    size_t i4 = ((size_t)bx * 256 + tid) * 4;
    f32x4 v = *(const f32x4*)&ag[i4];
    *(u32x2*)&Ab[i4] = pack4(v[0] * 0.125f, v[1] * 0.125f, v[2] * 0.125f, v[3] * 0.125f);
    return;
  }
  bx -= 128;
  {                                     // WoT[c][d] = Wout[d][c], 32x32 tiles
    int ct = bx % 32, dt = bx / 32;
    int r32 = tid >> 3, c4 = (tid & 7) * 4;
    f32x4 v = *(const f32x4*)&Wout[(size_t)(dt * 32 + r32) * 1024 + ct * 32 + c4];
#pragma unroll
    for (int i = 0; i < 4; i++) ldsT[r32][c4 + i] = v[i];
    __syncthreads();
    float o0 = ldsT[c4 + 0][r32], o1 = ldsT[c4 + 1][r32];
    float o2 = ldsT[c4 + 2][r32], o3 = ldsT[c4 + 3][r32];
    *(u32x2*)&WoT[(size_t)(ct * 32 + r32) * 1024 + dt * 32 + c4] = pack4(o0, o1, o2, o3);
  }
}

// ---------------- GEMM1: C[16384,3072] = Xb @ WqkvT^T ; scatter to Q,K,Vt -------------
// Q/K blocks: swapped operand roles -> D[j,n] so d is reg-consecutive (8B packed stores)
// V blocks:   normal roles -> D[n,j] so n is reg-consecutive (8B packed Vt stores)
__global__ __launch_bounds__(256, 2) void k_gemm_qkv(
    const unsigned short* __restrict__ A, const unsigned short* __restrict__ Bt,
    unsigned short* __restrict__ Q, unsigned short* __restrict__ Kd,
    unsigned short* __restrict__ Vt)
{
  __shared__ __align__(16) unsigned short lA[4096];
  __shared__ __align__(16) unsigned short lB[4096];
  const int tid = threadIdx.x, lane = tid & 63, w = tid >> 6;
  const int q = lane >> 4, r = lane & 15, wr = w >> 1, wc = w & 1;
  const int row0 = blockIdx.y * 128, col0 = blockIdx.x * 128;
  const bool qk = blockIdx.x < 16;
  const int c1 = w, c2 = w + 4;
  const int sr1 = c1 * 16 + (lane >> 2), sr2 = c2 * 16 + (lane >> 2);
  const int sk = 8 * (lane & 3);
  const unsigned short* gA1 = A + (size_t)(row0 + sr1) * 1024 + sk;
  const unsigned short* gA2 = A + (size_t)(row0 + sr2) * 1024 + sk;
  const unsigned short* gB1 = Bt + (size_t)(col0 + sr1) * 1024 + sk;
  const unsigned short* gB2 = Bt + (size_t)(col0 + sr2) * 1024 + sk;
  const unsigned short* sA = qk ? lB : lA;   // af source rows (j for Q/K, n for V)
  const unsigned short* sB = qk ? lA : lB;
  f32x4 acc[4][4];
  const f32x4 z = {0.f, 0.f, 0.f, 0.f};
#pragma unroll
  for (int i = 0; i < 4; i++)
#pragma unroll
    for (int j = 0; j < 4; j++) acc[i][j] = z;

  for (int k0 = 0; k0 < 1024; k0 += 32) {
    g2l16(gA1 + k0, &lA[c1 * 512]);
    g2l16(gA2 + k0, &lA[c2 * 512]);
    g2l16(gB1 + k0, &lB[c1 * 512]);
    g2l16(gB2 + k0, &lB[c2 * 512]);
    __syncthreads();
    bf16x8 af[4], bv[4];
#pragma unroll
    for (int rt = 0; rt < 4; rt++) af[rt] = *(const bf16x8*)&sA[(64 * wr + 16 * rt + r) * 32 + q * 8];
#pragma unroll
    for (int ct = 0; ct < 4; ct++) bv[ct] = *(const bf16x8*)&sB[(64 * wc + 16 * ct + r) * 32 + q * 8];
#pragma unroll
    for (int rt = 0; rt < 4; rt++)
#pragma unroll
      for (int ct = 0; ct < 4; ct++) MFMA16(acc[rt][ct], af[rt], bv[ct]);
    __syncthreads();
  }
  const int b = row0 >> 12;
  if (qk) {   // D[row=j_local, col=n_local]; d = j&63 reg-consecutive
    unsigned short* dst = (blockIdx.x < 8) ? Q : Kd;
    const int hbase = ((col0 & 1023) >> 6) + wr;   // j = (col0&1023) + 64*wr + ...
#pragma unroll
    for (int rt = 0; rt < 4; rt++)
#pragma unroll
      for (int ct = 0; ct < 4; ct++) {
        int d0 = 16 * rt + 4 * q;
        int n = (row0 & 4095) + 64 * wc + 16 * ct + r;
        u32x2 pk = pack4(acc[rt][ct][0], acc[rt][ct][1], acc[rt][ct][2], acc[rt][ct][3]);
        *(u32x2*)&dst[(((size_t)(b * 16 + hbase)) * 4096 + n) * 64 + d0] = pk;
      }
  } else {    // D[row=n, col=j]; pack 4 consecutive n into Vt[b,h,d,n]
#pragma unroll
    for (int rt = 0; rt < 4; rt++)
#pragma unroll
      for (int ct = 0; ct < 4; ct++) {
        int j = (col0 - 2048) + 64 * wc + 16 * ct + r;
        int h = j >> 6, d = j & 63;
        int nb = (row0 & 4095) + 64 * wr + 16 * rt + 4 * q;
        u32x2 pk = pack4(acc[rt][ct][0], acc[rt][ct][1], acc[rt][ct][2], acc[rt][ct][3]);
        *(u32x2*)&Vt[(((size_t)(b * 16 + h)) * 64 + d) * 4096 + nb] = pk;
      }
  }
}

// ------ qa: sim^T via swapped roles -> D[m,n]; softmax over m; QA[b,h,n,m] 8B stores --
__global__ __launch_bounds__(256, 2) void k_qa(
    const unsigned short* __restrict__ Q, const unsigned short* __restrict__ Ab,
    unsigned short* __restrict__ QA)
{
  const int tid = threadIdx.x, lane = tid & 63, w = tid >> 6;
  const int q = lane >> 4, r = lane & 15, wr = w >> 1, wc = w & 1;
  const int nt = blockIdx.x, h = blockIdx.y, b = blockIdx.z;
  const unsigned short* Qb = Q + (((size_t)(b * 16 + h)) * 4096 + nt * 128) * 64;
  const unsigned short* Ah = Ab + (size_t)h * 8192;
  f32x4 acc[4][4];
  const f32x4 z = {0.f, 0.f, 0.f, 0.f};
#pragma unroll
  for (int i = 0; i < 4; i++)
#pragma unroll
    for (int j = 0; j < 4; j++) acc[i][j] = z;
#pragma unroll
  for (int ks = 0; ks < 2; ks++) {
    bf16x8 af[4], bv[4];
#pragma unroll
    for (int rt = 0; rt < 4; rt++) af[rt] = ldg8(Ah + (size_t)(64 * wr + 16 * rt + r) * 64 + ks * 32 + q * 8);
#pragma unroll
    for (int ct = 0; ct < 4; ct++) bv[ct] = ldg8(Qb + (size_t)(64 * wc + 16 * ct + r) * 64 + ks * 32 + q * 8);
#pragma unroll
    for (int rt = 0; rt < 4; rt++)
#pragma unroll
      for (int ct = 0; ct < 4; ct++) MFMA16(acc[rt][ct], af[rt], bv[ct]);
  }
  // exp + column sums (sum over m = rows). |sim|<~0.2 -> no max subtraction.
  __shared__ float rs[2][128];
  float cs[4];
#pragma unroll
  for (int ct = 0; ct < 4; ct++) {
    float s = 0.f;
#pragma unroll
    for (int rt = 0; rt < 4; rt++)
#pragma unroll
      for (int reg = 0; reg < 4; reg++) {
        float e = __expf(acc[rt][ct][reg]);
        acc[rt][ct][reg] = e; s += e;
      }
    s += __shfl_xor(s, 16); s += __shfl_xor(s, 32);
    cs[ct] = s;
  }
  if (q == 0) {
#pragma unroll
    for (int ct = 0; ct < 4; ct++) rs[wr][64 * wc + 16 * ct + r] = cs[ct];
  }
  __syncthreads();
#pragma unroll
  for (int ct = 0; ct < 4; ct++) {
    int nl = 64 * wc + 16 * ct + r;
    float inv = 1.0f / (rs[0][nl] + rs[1][nl]);
    int n = nt * 128 + nl;
    size_t base = (((size_t)(b * 16 + h)) * 4096 + n) * 128;
#pragma unroll
    for (int rt = 0; rt < 4; rt++) {
      int m0 = 64 * wr + 16 * rt + 4 * q;
      u32x2 pk = pack4(acc[rt][ct][0] * inv, acc[rt][ct][1] * inv,
                       acc[rt][ct][2] * inv, acc[rt][ct][3] * inv);
      *(u32x2*)&QA[base + m0] = pk;
    }
  }
}

// ---- ak: swapped roles -> D[n,m]; mask+exp; E[b,h,m,n] 8B stores + atomic rowsums ----
__global__ __launch_bounds__(256, 2) void k_ak(
    const unsigned short* __restrict__ Kd, const unsigned short* __restrict__ Ab,
    const int* __restrict__ mask, unsigned short* __restrict__ E, float* __restrict__ rowsum)
{
  const int tid = threadIdx.x, lane = tid & 63, w = tid >> 6;
  const int q = lane >> 4, r = lane & 15, wr = w >> 1, wc = w & 1;
  const int nt = blockIdx.x, h = blockIdx.y, b = blockIdx.z;
  const unsigned short* Kb = Kd + (((size_t)(b * 16 + h)) * 4096 + nt * 128) * 64;
  const unsigned short* Ah = Ab + (size_t)h * 8192;
  f32x4 acc[4][4];
  const f32x4 z = {0.f, 0.f, 0.f, 0.f};
#pragma unroll
  for (int i = 0; i < 4; i++)
#pragma unroll
    for (int j = 0; j < 4; j++) acc[i][j] = z;
#pragma unroll
  for (int ks = 0; ks < 2; ks++) {
    bf16x8 af[4], bv[4];
#pragma unroll
    for (int rt = 0; rt < 4; rt++) af[rt] = ldg8(Kb + (size_t)(64 * wr + 16 * rt + r) * 64 + ks * 32 + q * 8);
#pragma unroll
    for (int ct = 0; ct < 4; ct++) bv[ct] = ldg8(Ah + (size_t)(64 * wc + 16 * ct + r) * 64 + ks * 32 + q * 8);
#pragma unroll
    for (int rt = 0; rt < 4; rt++)
#pragma unroll
      for (int ct = 0; ct < 4; ct++) MFMA16(acc[rt][ct], af[rt], bv[ct]);
  }
  // mask rows (n), exp, store unnormalized; column sums = sum over n (rows+blocks)
  __shared__ float rs[2][128];
  float cs[4] = {0.f, 0.f, 0.f, 0.f};
#pragma unroll
  for (int rt = 0; rt < 4; rt++) {
    const int4 mkv = *(const int4*)&mask[b * 4096 + nt * 128 + 64 * wr + 16 * rt + 4 * q];
    int mka[4] = {mkv.x, mkv.y, mkv.z, mkv.w};
#pragma unroll
    for (int ct = 0; ct < 4; ct++) {
#pragma unroll
      for (int reg = 0; reg < 4; reg++) {
        float e = mka[reg] ? __expf(acc[rt][ct][reg]) : 0.0f;
        acc[rt][ct][reg] = e; cs[ct] += e;
      }
    }
  }
#pragma unroll
  for (int ct = 0; ct < 4; ct++) {
    float s = cs[ct];
    s += __shfl_xor(s, 16); s += __shfl_xor(s, 32);
    cs[ct] = s;
  }
  if (q == 0) {
#pragma unroll
    for (int ct = 0; ct < 4; ct++) rs[wr][64 * wc + 16 * ct + r] = cs[ct];
  }
  // stores: pack 4 consecutive n (regs)
#pragma unroll
  for (int ct = 0; ct < 4; ct++) {
    int m = 64 * wc + 16 * ct + r;
    size_t base = (((size_t)(b * 16 + h)) * 128 + m) * 4096;
#pragma unroll
    for (int rt = 0; rt < 4; rt++) {
      int n0 = nt * 128 + 64 * wr + 16 * rt + 4 * q;
      u32x2 pk = pack4(acc[rt][ct][0], acc[rt][ct][1], acc[rt][ct][2], acc[rt][ct][3]);
      *(u32x2*)&E[base + n0] = pk;
    }
  }
  __syncthreads();
  if (tid < 128) atomicAdd(&rowsum[(b * 16 + h) * 128 + tid], rs[0][tid] + rs[1][tid]);
}

// ---- mix: MIX[g,m,n] = sum_h Wak[g,h]*E[h,m,n]/rowsum[h,m]  (4 elems/thread, 8B IO) --
__global__ __launch_bounds__(256) void k_mix(
    const unsigned short* __restrict__ E, const float* __restrict__ rowsum,
    const float* __restrict__ Wak, unsigned short* __restrict__ MIX)
{
  const int tid = threadIdx.x;
  const int m = blockIdx.y, b = blockIdx.z;
  __shared__ float wv[256];
  __shared__ float inv[16];
  wv[tid] = Wak[tid];
  if (tid < 16) inv[tid] = 1.0f / rowsum[(b * 16 + tid) * 128 + m];
  __syncthreads();
  const int n0 = (blockIdx.x * 256 + tid) * 4;
  float p[16][4];
#pragma unroll
  for (int h = 0; h < 16; h++) {
    u32x2 v = *(const u32x2*)&E[(((size_t)(b * 16 + h)) * 128 + m) * 4096 + n0];
    float iv = inv[h];
    p[h][0] = bf2f((unsigned short)(v.x & 0xffff)) * iv;
    p[h][1] = bf2f((unsigned short)(v.x >> 16)) * iv;
    p[h][2] = bf2f((unsigned short)(v.y & 0xffff)) * iv;
    p[h][3] = bf2f((unsigned short)(v.y >> 16)) * iv;
  }
#pragma unroll
  for (int g = 0; g < 16; g++) {
    float s0 = 0.f, s1 = 0.f, s2 = 0.f, s3 = 0.f;
#pragma unroll
    for (int h = 0; h < 16; h++) {
      float wgh = wv[g * 16 + h];
      s0 += wgh * p[h][0]; s1 += wgh * p[h][1]; s2 += wgh * p[h][2]; s3 += wgh * p[h][3];
    }
    *(u32x2*)&MIX[(((size_t)(b * 16 + g)) * 128 + m) * 4096 + n0] = pack4(s0, s1, s2, s3);
  }
}

// ------ AO_T[b,g,d,m] += MIX[b,g] @ V[b,g]  (K=4096, k-split x8, atomics) -------------
__global__ __launch_bounds__(256) void k_ao(
    const unsigned short* __restrict__ MIX, const unsigned short* __restrict__ Vt,
    float* __restrict__ AO)
{
  const int tid = threadIdx.x, lane = tid & 63, w4 = tid >> 6;
  const int q = lane >> 4, r = lane & 15;
  const int kc = blockIdx.x, g = blockIdx.y, b = blockIdx.z;
  const unsigned short* Abase = MIX + ((size_t)(b * 16 + g)) * 128 * 4096;
  const unsigned short* Bbase = Vt + ((size_t)(b * 16 + g)) * 64 * 4096;
  f32x4 acc[2][4];
  const f32x4 z = {0.f, 0.f, 0.f, 0.f};
#pragma unroll
  for (int i = 0; i < 2; i++)
#pragma unroll
    for (int j = 0; j < 4; j++) acc[i][j] = z;
  for (int n = kc * 512; n < kc * 512 + 512; n += 32) {
    bf16x8 af[2], bv[4];
#pragma unroll
    for (int rt = 0; rt < 2; rt++) af[rt] = ldg8(Abase + (size_t)(32 * w4 + 16 * rt + r) * 4096 + n + q * 8);
#pragma unroll
    for (int ct = 0; ct < 4; ct++) bv[ct] = ldg8(Bbase + (size_t)(16 * ct + r) * 4096 + n + q * 8);
#pragma unroll
    for (int rt = 0; rt < 2; rt++)
#pragma unroll
      for (int ct = 0; ct < 4; ct++) MFMA16(acc[rt][ct], af[rt], bv[ct]);
  }
#pragma unroll
  for (int rt = 0; rt < 2; rt++)
#pragma unroll
    for (int ct = 0; ct < 4; ct++)
#pragma unroll
      for (int reg = 0; reg < 4; reg++) {
        int m = 32 * w4 + 16 * rt + 4 * q + reg, d = 16 * ct + r;
        atomicAdd(&AO[(((size_t)(b * 16 + g)) * 64 + d) * 128 + m], acc[rt][ct][reg]);
      }
}

// ---- mixqa: QAmix[g,plane] = sum_h Wqa[g,h]*QA[h,plane]  (4 elems/thread, 8B IO) -----
__global__ __launch_bounds__(256) void k_mixqa(
    const unsigned short* __restrict__ QA, const float* __restrict__ Wqa,
    unsigned short* __restrict__ QAmix)
{
  const int tid = threadIdx.x;
  const int b = blockIdx.y;
  __shared__ float wv[256];
  wv[tid] = Wqa[tid];
  __syncthreads();
  const size_t i0 = ((size_t)blockIdx.x * 256 + tid) * 4;   // plane 524288 elems
  float p[16][4];
#pragma unroll
  for (int h = 0; h < 16; h++) {
    u32x2 v = *(const u32x2*)&QA[((size_t)(b * 16 + h)) * 524288 + i0];
    p[h][0] = bf2f((unsigned short)(v.x & 0xffff));
    p[h][1] = bf2f((unsigned short)(v.x >> 16));
    p[h][2] = bf2f((unsigned short)(v.y & 0xffff));
    p[h][3] = bf2f((unsigned short)(v.y >> 16));
  }
#pragma unroll
  for (int g = 0; g < 16; g++) {
    float s0 = 0.f, s1 = 0.f, s2 = 0.f, s3 = 0.f;
#pragma unroll
    for (int h = 0; h < 16; h++) {
      float wgh = wv[g * 16 + h];
      s0 += wgh * p[h][0]; s1 += wgh * p[h][1]; s2 += wgh * p[h][2]; s3 += wgh * p[h][3];
    }
    *(u32x2*)&QAmix[((size_t)(b * 16 + g)) * 524288 + i0] = pack4(s0, s1, s2, s3);
  }
}

// ---- o1: swapped roles -> D[d,n]; out1[b,n,g*64+d] 8B stores; reads AO_T fp32 --------
__global__ __launch_bounds__(256) void k_o1(
    const unsigned short* __restrict__ QAmix, const float* __restrict__ AOt,
    unsigned short* __restrict__ out1)
{
  const int tid = threadIdx.x, lane = tid & 63, w4 = tid >> 6;
  const int q = lane >> 4, r = lane & 15;
  const int nt = blockIdx.x, g = blockIdx.y, b = blockIdx.z;
  const unsigned short* Bbase = QAmix + (((size_t)(b * 16 + g)) * 4096 + nt * 128) * 128;
  const float* Abase = AOt + ((size_t)(b * 16 + g)) * 8192;   // [d][m]
  f32x4 acc[4][2];
  const f32x4 z = {0.f, 0.f, 0.f, 0.f};
#pragma unroll
  for (int i = 0; i < 4; i++)
#pragma unroll
    for (int j = 0; j < 2; j++) acc[i][j] = z;
#pragma unroll
  for (int ks = 0; ks < 4; ks++) {
    bf16x8 af[4], bv[2];
#pragma unroll
    for (int rt = 0; rt < 4; rt++) {
      const float* p = Abase + (size_t)(16 * rt + r) * 128 + ks * 32 + q * 8;
      f32x4 f0 = *(const f32x4*)p;
      f32x4 f1 = *(const f32x4*)(p + 4);
      bf16x8 t;
#pragma unroll
      for (int jj = 0; jj < 4; jj++) { t[jj] = (__bf16)f0[jj]; t[4 + jj] = (__bf16)f1[jj]; }
      af[rt] = t;
    }
#pragma unroll
    for (int ct = 0; ct < 2; ct++)
      bv[ct] = ldg8(Bbase + (size_t)(32 * w4 + 16 * ct + r) * 128 + ks * 32 + q * 8);
#pragma unroll
    for (int rt = 0; rt < 4; rt++)
#pragma unroll
      for (int ct = 0; ct < 2; ct++) MFMA16(acc[rt][ct], af[rt], bv[ct]);
  }
#pragma unroll
  for (int ct = 0; ct < 2; ct++) {
    int n = nt * 128 + 32 * w4 + 16 * ct + r;
    size_t base = ((size_t)b * 4096 + n) * 1024 + g * 64;
#pragma unroll
    for (int rt = 0; rt < 4; rt++) {
      int d0 = 16 * rt + 4 * q;
      u32x2 pk = pack4(acc[rt][ct][0], acc[rt][ct][1], acc[rt][ct][2], acc[rt][ct][3]);
      *(u32x2*)&out1[base + d0] = pk;
    }
  }
}

// ------- fin2: out[16384,1024] = out1[16384,1024] @ WoT^T, mask rows, fp32 -----------
__global__ __launch_bounds__(256, 2) void k_fin2(
    const unsigned short* __restrict__ A, const unsigned short* __restrict__ Bt,
    const int* __restrict__ mask, float* __restrict__ out)
{
  __shared__ __align__(16) unsigned short lA[4096];
  __shared__ __align__(16) unsigned short lB[4096];
  const int tid = threadIdx.x, lane = tid & 63, w = tid >> 6;
  const int q = lane >> 4, r = lane & 15, wr = w >> 1, wc = w & 1;
  const int row0 = blockIdx.y * 128, col0 = blockIdx.x * 128;
  const int c1 = w, c2 = w + 4;
  const int sr1 = c1 * 16 + (lane >> 2), sr2 = c2 * 16 + (lane >> 2);
  const int sk = 8 * (lane & 3);
  const unsigned short* gA1 = A + (size_t)(row0 + sr1) * 1024 + sk;
  const unsigned short* gA2 = A + (size_t)(row0 + sr2) * 1024 + sk;
  const unsigned short* gB1 = Bt + (size_t)(col0 + sr1) * 1024 + sk;
  const unsigned short* gB2 = Bt + (size_t)(col0 + sr2) * 1024 + sk;
  f32x4 acc[4][4];
  const f32x4 z = {0.f, 0.f, 0.f, 0.f};
#pragma unroll
  for (int i = 0; i < 4; i++)
#pragma unroll
    for (int j = 0; j < 4; j++) acc[i][j] = z;
  for (int k0 = 0; k0 < 1024; k0 += 32) {
    g2l16(gA1 + k0, &lA[c1 * 512]);
    g2l16(gA2 + k0, &lA[c2 * 512]);
    g2l16(gB1 + k0, &lB[c1 * 512]);
    g2l16(gB2 + k0, &lB[c2 * 512]);
    __syncthreads();
    bf16x8 af[4], bv[4];
#pragma unroll
    for (int rt = 0; rt < 4; rt++) af[rt] = *(const bf16x8*)&lA[(64 * wr + 16 * rt + r) * 32 + q * 8];
#pragma unroll
    for (int ct = 0; ct < 4; ct++) bv[ct] = *(const bf16x8*)&lB[(64 * wc + 16 * ct + r) * 32 + q * 8];
#pragma unroll
    for (int rt = 0; rt < 4; rt++)
#pragma unroll
      for (int ct = 0; ct < 4; ct++) MFMA16(acc[rt][ct], af[rt], bv[ct]);
    __syncthreads();
  }
#pragma unroll
  for (int rt = 0; rt < 4; rt++)
#pragma unroll
    for (int reg = 0; reg < 4; reg++) {
      int row = row0 + 64 * wr + 16 * rt + 4 * q + reg;
      int mv = mask[row];
#pragma unroll
      for (int ct = 0; ct < 4; ct++) {
        int c = col0 + 64 * wc + 16 * ct + r;
        out[(size_t)row * 1024 + c] = mv ? acc[rt][ct][reg] : 0.0f;
      }
    }
}

// =====================================================================================
extern "C" void kernel_launch(void* const* d_in, const int* in_sizes, int n_in,
                              void* d_out, int out_size, void* d_ws, size_t ws_size,
                              hipStream_t stream) {
  const float* x    = (const float*)d_in[0];
  const int*   mask = (const int*)d_in[1];
  const float* Wqkv = (const float*)d_in[2];
  const float* ag   = (const float*)d_in[3];
  const float* Wqa  = (const float*)d_in[4];
  const float* Wak  = (const float*)d_in[5];
  const float* Wout = (const float*)d_in[6];
  float* out = (float*)d_out;
  char* ws = (char*)d_ws;

  // workspace layout, lifetime-overlapped; total 239,370,240 B
  unsigned short* QA    = (unsigned short*)(ws + 0);           // [k_qa -> k_mixqa]
  unsigned short* QQ    = (unsigned short*)(ws + 67108864);    // Q [gemm -> qa]
  unsigned short* KK    = (unsigned short*)(ws + 67108864 + 33554432);  // K [gemm -> ak]
  unsigned short* MIX   = QQ;                                  // [mix -> ao] (spans QQ+KK)
  unsigned short* out1  = QQ;                                  // [o1 -> fin2]
  unsigned short* VT    = (unsigned short*)(ws + 134217728);   // Vt [gemm -> ao]
  unsigned short* Xb    = (unsigned short*)(ws + 167772160);   // [prep -> gemm]
  unsigned short* WqkvT = (unsigned short*)(ws + 167772160 + 33554432);
  unsigned short* E     = Xb;                                  // [ak -> mix]
  unsigned short* QAmix = Xb;                                  // [mixqa -> o1]
  char* sm = ws + 234881024;
  unsigned short* Ab  = (unsigned short*)(sm);                 // 256 KB
  unsigned short* WoT = (unsigned short*)(sm + 262144);        // 2 MB
  float* rowsum = (float*)(sm + 262144 + 2097152);             // 32 KB
  float* AOt    = (float*)(sm + 262144 + 2097152 + 32768);     // 2 MB  [b,g,d,m] fp32

  hipMemsetAsync(rowsum, 0, 4 * 16 * 128 * 4, stream);
  hipMemsetAsync(AOt, 0, 4 * 16 * 128 * 64 * 4, stream);

  k_prep<<<20608, 256, 0, stream>>>(x, Wqkv, ag, Wout, Xb, WqkvT, Ab, WoT);
  k_gemm_qkv<<<dim3(24, 128), 256, 0, stream>>>(Xb, WqkvT, QQ, KK, VT);
  k_qa<<<dim3(32, 16, 4), 256, 0, stream>>>(QQ, Ab, QA);
  k_ak<<<dim3(32, 16, 4), 256, 0, stream>>>(KK, Ab, mask, E, rowsum);
  k_mix<<<dim3(4, 128, 4), 256, 0, stream>>>(E, rowsum, Wak, MIX);
  k_ao<<<dim3(8, 16, 4), 256, 0, stream>>>(MIX, VT, AOt);
  k_mixqa<<<dim3(512, 4), 256, 0, stream>>>(QA, Wqa, QAmix);
  k_o1<<<dim3(32, 16, 4), 256, 0, stream>>>(QAmix, AOt, out1);
  k_fin2<<<dim3(8, 128), 256, 0, stream>>>(out1, WoT, mask, out);
}

// Round 4
// 493.214 us; speedup vs baseline: 1.2665x; 1.1095x over previous
//
#include <hip/hip_runtime.h>
#include <stdint.h>

#define DEVI __device__ __forceinline__

typedef __bf16 bf16x8 __attribute__((ext_vector_type(8)));
typedef float  f32x4  __attribute__((ext_vector_type(4)));
typedef unsigned int u32x2 __attribute__((ext_vector_type(2)));

// B=4, N=4096, DIM=1024, H=16, D=64, M=128, DIM_INNER=1024, SCALE=0.125

DEVI unsigned short f2bf(float f) {  // RNE f32->bf16
  union { float f; unsigned int u; } c; c.f = f;
  return (unsigned short)((c.u + 0x7fffu + ((c.u >> 16) & 1u)) >> 16);
}
DEVI float bf2f(unsigned short s) {
  union { unsigned int u; float f; } c; c.u = ((unsigned int)s) << 16;
  return c.f;
}
DEVI u32x2 pack4(float a, float b, float c, float d) {
  u32x2 r;
  r.x = (unsigned)f2bf(a) | ((unsigned)f2bf(b) << 16);
  r.y = (unsigned)f2bf(c) | ((unsigned)f2bf(d) << 16);
  return r;
}
DEVI bf16x8 ldg8(const unsigned short* p) { return *(const bf16x8*)p; }

DEVI void g2l16(const void* g, void* l) {
  __builtin_amdgcn_global_load_lds(
      (const __attribute__((address_space(1))) unsigned int*)g,
      (__attribute__((address_space(3))) unsigned int*)l, 16, 0, 0);
}

#define MFMA16(acc, a, b) acc = __builtin_amdgcn_mfma_f32_16x16x32_bf16((a), (b), (acc), 0, 0, 0)

// ---------------- prep: fp32->bf16 cvt + LDS-tiled transposes + rowsum zero -----------
// blocks [0,16384): x | [16384,19456): Wqkv^T | [19456,19584): agent*SCALE
// | [19584,20608): Wout^T | [20608,20616): zero rowsum
__global__ __launch_bounds__(256) void k_prep(
    const float* __restrict__ x, const float* __restrict__ Wqkv,
    const float* __restrict__ ag, const float* __restrict__ Wout,
    unsigned short* __restrict__ Xb, unsigned short* __restrict__ WqkvT,
    unsigned short* __restrict__ Ab, unsigned short* __restrict__ WoT,
    float* __restrict__ rowsum)
{
  __shared__ float ldsT[32][33];
  const int tid = threadIdx.x;
  int bx = blockIdx.x;
  if (bx < 16384) {                     // x: 16.7M elems, 4/thread
    size_t i4 = ((size_t)bx * 256 + tid) * 4;
    f32x4 v = *(const f32x4*)&x[i4];
    *(u32x2*)&Xb[i4] = pack4(v[0], v[1], v[2], v[3]);
    return;
  }
  bx -= 16384;
  if (bx < 3072) {                      // WqkvT[j][k] = Wqkv[k][j], 32x32 tiles
    int jt = bx % 96, kt = bx / 96;
    int r32 = tid >> 3, c4 = (tid & 7) * 4;
    f32x4 v = *(const f32x4*)&Wqkv[(size_t)(kt * 32 + r32) * 3072 + jt * 32 + c4];
#pragma unroll
    for (int i = 0; i < 4; i++) ldsT[r32][c4 + i] = v[i];
    __syncthreads();
    float o0 = ldsT[c4 + 0][r32], o1 = ldsT[c4 + 1][r32];
    float o2 = ldsT[c4 + 2][r32], o3 = ldsT[c4 + 3][r32];
    *(u32x2*)&WqkvT[(size_t)(jt * 32 + r32) * 1024 + kt * 32 + c4] = pack4(o0, o1, o2, o3);
    return;
  }
  bx -= 3072;
  if (bx < 128) {                       // agent tokens * SCALE
    size_t i4 = ((size_t)bx * 256 + tid) * 4;
    f32x4 v = *(const f32x4*)&ag[i4];
    *(u32x2*)&Ab[i4] = pack4(v[0] * 0.125f, v[1] * 0.125f, v[2] * 0.125f, v[3] * 0.125f);
    return;
  }
  bx -= 128;
  if (bx < 1024) {                      // WoT[c][d] = Wout[d][c], 32x32 tiles
    int ct = bx % 32, dt = bx / 32;
    int r32 = tid >> 3, c4 = (tid & 7) * 4;
    f32x4 v = *(const f32x4*)&Wout[(size_t)(dt * 32 + r32) * 1024 + ct * 32 + c4];
#pragma unroll
    for (int i = 0; i < 4; i++) ldsT[r32][c4 + i] = v[i];
    __syncthreads();
    float o0 = ldsT[c4 + 0][r32], o1 = ldsT[c4 + 1][r32];
    float o2 = ldsT[c4 + 2][r32], o3 = ldsT[c4 + 3][r32];
    *(u32x2*)&WoT[(size_t)(ct * 32 + r32) * 1024 + dt * 32 + c4] = pack4(o0, o1, o2, o3);
    return;
  }
  bx -= 1024;
  {                                     // zero rowsum (8 blocks x 1024 floats)
    const f32x4 z = {0.f, 0.f, 0.f, 0.f};
    *(f32x4*)&rowsum[((size_t)bx * 256 + tid) * 4] = z;
  }
}

// ---------------- GEMM1: C[16384,3072] = Xb @ WqkvT^T ; scatter to Q,K,Vt -------------
// grid (x=row 128, y=col 24): consecutive blocks share B col-tile (L2-hot).
// Q/K col-blocks: swapped roles -> D[j,n], d reg-consecutive. V: D[n,j], n reg-consec.
__global__ __launch_bounds__(256, 2) void k_gemm_qkv(
    const unsigned short* __restrict__ A, const unsigned short* __restrict__ Bt,
    unsigned short* __restrict__ Q, unsigned short* __restrict__ Kd,
    unsigned short* __restrict__ Vt)
{
  __shared__ __align__(16) unsigned short lA[4096];
  __shared__ __align__(16) unsigned short lB[4096];
  const int tid = threadIdx.x, lane = tid & 63, w = tid >> 6;
  const int q = lane >> 4, r = lane & 15, wr = w >> 1, wc = w & 1;
  const int row0 = blockIdx.x * 128, col0 = blockIdx.y * 128;
  const bool qk = blockIdx.y < 16;
  const int c1 = w, c2 = w + 4;
  const int sr1 = c1 * 16 + (lane >> 2), sr2 = c2 * 16 + (lane >> 2);
  const int sk = 8 * (lane & 3);
  const unsigned short* gA1 = A + (size_t)(row0 + sr1) * 1024 + sk;
  const unsigned short* gA2 = A + (size_t)(row0 + sr2) * 1024 + sk;
  const unsigned short* gB1 = Bt + (size_t)(col0 + sr1) * 1024 + sk;
  const unsigned short* gB2 = Bt + (size_t)(col0 + sr2) * 1024 + sk;
  const unsigned short* sA = qk ? lB : lA;   // af rows: j for Q/K, n for V
  const unsigned short* sB = qk ? lA : lB;
  f32x4 acc[4][4];
  const f32x4 z = {0.f, 0.f, 0.f, 0.f};
#pragma unroll
  for (int i = 0; i < 4; i++)
#pragma unroll
    for (int j = 0; j < 4; j++) acc[i][j] = z;

  for (int k0 = 0; k0 < 1024; k0 += 32) {
    g2l16(gA1 + k0, &lA[c1 * 512]);
    g2l16(gA2 + k0, &lA[c2 * 512]);
    g2l16(gB1 + k0, &lB[c1 * 512]);
    g2l16(gB2 + k0, &lB[c2 * 512]);
    __syncthreads();
    bf16x8 af[4], bv[4];
#pragma unroll
    for (int rt = 0; rt < 4; rt++) af[rt] = *(const bf16x8*)&sA[(64 * wr + 16 * rt + r) * 32 + q * 8];
#pragma unroll
    for (int ct = 0; ct < 4; ct++) bv[ct] = *(const bf16x8*)&sB[(64 * wc + 16 * ct + r) * 32 + q * 8];
#pragma unroll
    for (int rt = 0; rt < 4; rt++)
#pragma unroll
      for (int ct = 0; ct < 4; ct++) MFMA16(acc[rt][ct], af[rt], bv[ct]);
    __syncthreads();
  }
  const int b = row0 >> 12;
  if (qk) {   // D[row=j_local, col=n_local]
    unsigned short* dst = (blockIdx.y < 8) ? Q : Kd;
    const int hbase = ((col0 & 1023) >> 6) + wr;
#pragma unroll
    for (int rt = 0; rt < 4; rt++)
#pragma unroll
      for (int ct = 0; ct < 4; ct++) {
        int d0 = 16 * rt + 4 * q;
        int n = (row0 & 4095) + 64 * wc + 16 * ct + r;
        u32x2 pk = pack4(acc[rt][ct][0], acc[rt][ct][1], acc[rt][ct][2], acc[rt][ct][3]);
        *(u32x2*)&dst[(((size_t)(b * 16 + hbase)) * 4096 + n) * 64 + d0] = pk;
      }
  } else {    // D[row=n, col=j]; pack 4 consecutive n into Vt[b,h,d,n]
#pragma unroll
    for (int rt = 0; rt < 4; rt++)
#pragma unroll
      for (int ct = 0; ct < 4; ct++) {
        int j = (col0 - 2048) + 64 * wc + 16 * ct + r;
        int h = j >> 6, d = j & 63;
        int nb = (row0 & 4095) + 64 * wr + 16 * rt + 4 * q;
        u32x2 pk = pack4(acc[rt][ct][0], acc[rt][ct][1], acc[rt][ct][2], acc[rt][ct][3]);
        *(u32x2*)&Vt[(((size_t)(b * 16 + h)) * 64 + d) * 4096 + nb] = pk;
      }
  }
}

// ------- qk: fused qa (softmax over m -> QA[b,h,n,m]) + ak (mask+exp -> E[b,h,m,n]) ---
__global__ __launch_bounds__(256, 2) void k_qk(
    const unsigned short* __restrict__ Q, const unsigned short* __restrict__ Kd,
    const unsigned short* __restrict__ Ab, const int* __restrict__ mask,
    unsigned short* __restrict__ QA, unsigned short* __restrict__ E,
    float* __restrict__ rowsum)
{
  const int tid = threadIdx.x, lane = tid & 63, w = tid >> 6;
  const int q = lane >> 4, r = lane & 15, wr = w >> 1, wc = w & 1;
  const int nt = blockIdx.x, h = blockIdx.y, b = blockIdx.z;
  const unsigned short* Qb = Q + (((size_t)(b * 16 + h)) * 4096 + nt * 128) * 64;
  const unsigned short* Kb = Kd + (((size_t)(b * 16 + h)) * 4096 + nt * 128) * 64;
  const unsigned short* Ah = Ab + (size_t)h * 8192;
  __shared__ float rs[2][128];
  const f32x4 z = {0.f, 0.f, 0.f, 0.f};

  // ================= qa part: D[m,n] (A=agent rows m, B=Q rows n) =================
  {
    f32x4 acc[4][4];
#pragma unroll
    for (int i = 0; i < 4; i++)
#pragma unroll
      for (int j = 0; j < 4; j++) acc[i][j] = z;
#pragma unroll
    for (int ks = 0; ks < 2; ks++) {
      bf16x8 af[4], bv[4];
#pragma unroll
      for (int rt = 0; rt < 4; rt++) af[rt] = ldg8(Ah + (size_t)(64 * wr + 16 * rt + r) * 64 + ks * 32 + q * 8);
#pragma unroll
      for (int ct = 0; ct < 4; ct++) bv[ct] = ldg8(Qb + (size_t)(64 * wc + 16 * ct + r) * 64 + ks * 32 + q * 8);
#pragma unroll
      for (int rt = 0; rt < 4; rt++)
#pragma unroll
        for (int ct = 0; ct < 4; ct++) MFMA16(acc[rt][ct], af[rt], bv[ct]);
    }
    float cs[4];
#pragma unroll
    for (int ct = 0; ct < 4; ct++) {
      float s = 0.f;
#pragma unroll
      for (int rt = 0; rt < 4; rt++)
#pragma unroll
        for (int reg = 0; reg < 4; reg++) {
          float e = __expf(acc[rt][ct][reg]);
          acc[rt][ct][reg] = e; s += e;
        }
      s += __shfl_xor(s, 16); s += __shfl_xor(s, 32);
      cs[ct] = s;
    }
    if (q == 0) {
#pragma unroll
      for (int ct = 0; ct < 4; ct++) rs[wr][64 * wc + 16 * ct + r] = cs[ct];
    }
    __syncthreads();
#pragma unroll
    for (int ct = 0; ct < 4; ct++) {
      int nl = 64 * wc + 16 * ct + r;
      float inv = 1.0f / (rs[0][nl] + rs[1][nl]);
      int n = nt * 128 + nl;
      size_t base = (((size_t)(b * 16 + h)) * 4096 + n) * 128;
#pragma unroll
      for (int rt = 0; rt < 4; rt++) {
        int m0 = 64 * wr + 16 * rt + 4 * q;
        u32x2 pk = pack4(acc[rt][ct][0] * inv, acc[rt][ct][1] * inv,
                         acc[rt][ct][2] * inv, acc[rt][ct][3] * inv);
        *(u32x2*)&QA[base + m0] = pk;
      }
    }
  }
  __syncthreads();   // rs WAR hazard between sections

  // ================= ak part: D[n,m] (A=K rows n, B=agent rows m) =================
  {
    f32x4 acc[4][4];
#pragma unroll
    for (int i = 0; i < 4; i++)
#pragma unroll
      for (int j = 0; j < 4; j++) acc[i][j] = z;
#pragma unroll
    for (int ks = 0; ks < 2; ks++) {
      bf16x8 af[4], bv[4];
#pragma unroll
      for (int rt = 0; rt < 4; rt++) af[rt] = ldg8(Kb + (size_t)(64 * wr + 16 * rt + r) * 64 + ks * 32 + q * 8);
#pragma unroll
      for (int ct = 0; ct < 4; ct++) bv[ct] = ldg8(Ah + (size_t)(64 * wc + 16 * ct + r) * 64 + ks * 32 + q * 8);
#pragma unroll
      for (int rt = 0; rt < 4; rt++)
#pragma unroll
        for (int ct = 0; ct < 4; ct++) MFMA16(acc[rt][ct], af[rt], bv[ct]);
    }
    float cs[4] = {0.f, 0.f, 0.f, 0.f};
#pragma unroll
    for (int rt = 0; rt < 4; rt++) {
      const int4 mkv = *(const int4*)&mask[b * 4096 + nt * 128 + 64 * wr + 16 * rt + 4 * q];
      int mka[4] = {mkv.x, mkv.y, mkv.z, mkv.w};
#pragma unroll
      for (int ct = 0; ct < 4; ct++) {
#pragma unroll
        for (int reg = 0; reg < 4; reg++) {
          float e = mka[reg] ? __expf(acc[rt][ct][reg]) : 0.0f;
          acc[rt][ct][reg] = e; cs[ct] += e;
        }
      }
    }
#pragma unroll
    for (int ct = 0; ct < 4; ct++) {
      float s = cs[ct];
      s += __shfl_xor(s, 16); s += __shfl_xor(s, 32);
      cs[ct] = s;
    }
    if (q == 0) {
#pragma unroll
      for (int ct = 0; ct < 4; ct++) rs[wr][64 * wc + 16 * ct + r] = cs[ct];
    }
#pragma unroll
    for (int ct = 0; ct < 4; ct++) {
      int m = 64 * wc + 16 * ct + r;
      size_t base = (((size_t)(b * 16 + h)) * 128 + m) * 4096;
#pragma unroll
      for (int rt = 0; rt < 4; rt++) {
        int n0 = nt * 128 + 64 * wr + 16 * rt + 4 * q;
        u32x2 pk = pack4(acc[rt][ct][0], acc[rt][ct][1], acc[rt][ct][2], acc[rt][ct][3]);
        *(u32x2*)&E[base + n0] = pk;
      }
    }
    __syncthreads();
    if (tid < 128) atomicAdd(&rowsum[(b * 16 + h) * 128 + tid], rs[0][tid] + rs[1][tid]);
  }
}

// ---- mix: MIX[g,m,n] = sum_h Wak[g,h]*E[h,m,n]/rowsum[h,m]  (4 elems/thread, 8B IO) --
__global__ __launch_bounds__(256) void k_mix(
    const unsigned short* __restrict__ E, const float* __restrict__ rowsum,
    const float* __restrict__ Wak, unsigned short* __restrict__ MIX)
{
  const int tid = threadIdx.x;
  const int m = blockIdx.y, b = blockIdx.z;
  __shared__ float wv[256];
  __shared__ float inv[16];
  wv[tid] = Wak[tid];
  if (tid < 16) inv[tid] = 1.0f / rowsum[(b * 16 + tid) * 128 + m];
  __syncthreads();
  const int n0 = (blockIdx.x * 256 + tid) * 4;
  float p[16][4];
#pragma unroll
  for (int h = 0; h < 16; h++) {
    u32x2 v = *(const u32x2*)&E[(((size_t)(b * 16 + h)) * 128 + m) * 4096 + n0];
    float iv = inv[h];
    p[h][0] = bf2f((unsigned short)(v.x & 0xffff)) * iv;
    p[h][1] = bf2f((unsigned short)(v.x >> 16)) * iv;
    p[h][2] = bf2f((unsigned short)(v.y & 0xffff)) * iv;
    p[h][3] = bf2f((unsigned short)(v.y >> 16)) * iv;
  }
#pragma unroll
  for (int g = 0; g < 16; g++) {
    float s0 = 0.f, s1 = 0.f, s2 = 0.f, s3 = 0.f;
#pragma unroll
    for (int h = 0; h < 16; h++) {
      float wgh = wv[g * 16 + h];
      s0 += wgh * p[h][0]; s1 += wgh * p[h][1]; s2 += wgh * p[h][2]; s3 += wgh * p[h][3];
    }
    *(u32x2*)&MIX[(((size_t)(b * 16 + g)) * 128 + m) * 4096 + n0] = pack4(s0, s1, s2, s3);
  }
}

// ------ k_ao: partial AO_T planes P[kc][b,g,d,m] = MIX[b,g] @ V[b,g] (k-chunk) --------
__global__ __launch_bounds__(256) void k_ao(
    const unsigned short* __restrict__ MIX, const unsigned short* __restrict__ Vt,
    float* __restrict__ P)
{
  const int tid = threadIdx.x, lane = tid & 63, w4 = tid >> 6;
  const int q = lane >> 4, r = lane & 15;
  const int kc = blockIdx.x, g = blockIdx.y, b = blockIdx.z;
  const unsigned short* Abase = MIX + ((size_t)(b * 16 + g)) * 128 * 4096;
  const unsigned short* Bbase = Vt + ((size_t)(b * 16 + g)) * 64 * 4096;
  f32x4 acc[2][4];
  const f32x4 z = {0.f, 0.f, 0.f, 0.f};
#pragma unroll
  for (int i = 0; i < 2; i++)
#pragma unroll
    for (int j = 0; j < 4; j++) acc[i][j] = z;
  for (int n = kc * 512; n < kc * 512 + 512; n += 32) {
    bf16x8 af[2], bv[4];
#pragma unroll
    for (int rt = 0; rt < 2; rt++) af[rt] = ldg8(Abase + (size_t)(32 * w4 + 16 * rt + r) * 4096 + n + q * 8);
#pragma unroll
    for (int ct = 0; ct < 4; ct++) bv[ct] = ldg8(Bbase + (size_t)(16 * ct + r) * 4096 + n + q * 8);
#pragma unroll
    for (int rt = 0; rt < 2; rt++)
#pragma unroll
      for (int ct = 0; ct < 4; ct++) MFMA16(acc[rt][ct], af[rt], bv[ct]);
  }
  float* Pp = P + (size_t)kc * 524288 + ((size_t)(b * 16 + g)) * 8192;
#pragma unroll
  for (int rt = 0; rt < 2; rt++)
#pragma unroll
    for (int ct = 0; ct < 4; ct++) {
      int m0 = 32 * w4 + 16 * rt + 4 * q, d = 16 * ct + r;
      *(f32x4*)&Pp[(size_t)d * 128 + m0] = acc[rt][ct];   // regs = consecutive m
    }
}

// ------ aored: AOt = sum_kc P[kc]  (524288 fp32) --------------------------------------
__global__ __launch_bounds__(256) void k_aored(
    const float* __restrict__ P, float* __restrict__ AOt)
{
  size_t i = ((size_t)blockIdx.x * 256 + threadIdx.x) * 4;
  f32x4 s = *(const f32x4*)&P[i];
#pragma unroll
  for (int kc = 1; kc < 8; kc++) {
    f32x4 v = *(const f32x4*)&P[(size_t)kc * 524288 + i];
    s[0] += v[0]; s[1] += v[1]; s[2] += v[2]; s[3] += v[3];
  }
  *(f32x4*)&AOt[i] = s;
}

// ---- mixqa: QAmix[g,plane] = sum_h Wqa[g,h]*QA[h,plane]  (4 elems/thread, 8B IO) -----
__global__ __launch_bounds__(256) void k_mixqa(
    const unsigned short* __restrict__ QA, const float* __restrict__ Wqa,
    unsigned short* __restrict__ QAmix)
{
  const int tid = threadIdx.x;
  const int b = blockIdx.y;
  __shared__ float wv[256];
  wv[tid] = Wqa[tid];
  __syncthreads();
  const size_t i0 = ((size_t)blockIdx.x * 256 + tid) * 4;   // plane 524288 elems
  float p[16][4];
#pragma unroll
  for (int h = 0; h < 16; h++) {
    u32x2 v = *(const u32x2*)&QA[((size_t)(b * 16 + h)) * 524288 + i0];
    p[h][0] = bf2f((unsigned short)(v.x & 0xffff));
    p[h][1] = bf2f((unsigned short)(v.x >> 16));
    p[h][2] = bf2f((unsigned short)(v.y & 0xffff));
    p[h][3] = bf2f((unsigned short)(v.y >> 16));
  }
#pragma unroll
  for (int g = 0; g < 16; g++) {
    float s0 = 0.f, s1 = 0.f, s2 = 0.f, s3 = 0.f;
#pragma unroll
    for (int h = 0; h < 16; h++) {
      float wgh = wv[g * 16 + h];
      s0 += wgh * p[h][0]; s1 += wgh * p[h][1]; s2 += wgh * p[h][2]; s3 += wgh * p[h][3];
    }
    *(u32x2*)&QAmix[((size_t)(b * 16 + g)) * 524288 + i0] = pack4(s0, s1, s2, s3);
  }
}

// ---- o1: swapped roles -> D[d,n]; out1[b,n,g*64+d] 8B stores; reads AO_T fp32 --------
__global__ __launch_bounds__(256) void k_o1(
    const unsigned short* __restrict__ QAmix, const float* __restrict__ AOt,
    unsigned short* __restrict__ out1)
{
  const int tid = threadIdx.x, lane = tid & 63, w4 = tid >> 6;
  const int q = lane >> 4, r = lane & 15;
  const int nt = blockIdx.x, g = blockIdx.y, b = blockIdx.z;
  const unsigned short* Bbase = QAmix + (((size_t)(b * 16 + g)) * 4096 + nt * 128) * 128;
  const float* Abase = AOt + ((size_t)(b * 16 + g)) * 8192;   // [d][m]
  f32x4 acc[4][2];
  const f32x4 z = {0.f, 0.f, 0.f, 0.f};
#pragma unroll
  for (int i = 0; i < 4; i++)
#pragma unroll
    for (int j = 0; j < 2; j++) acc[i][j] = z;
#pragma unroll
  for (int ks = 0; ks < 4; ks++) {
    bf16x8 af[4], bv[2];
#pragma unroll
    for (int rt = 0; rt < 4; rt++) {
      const float* p = Abase + (size_t)(16 * rt + r) * 128 + ks * 32 + q * 8;
      f32x4 f0 = *(const f32x4*)p;
      f32x4 f1 = *(const f32x4*)(p + 4);
      bf16x8 t;
#pragma unroll
      for (int jj = 0; jj < 4; jj++) { t[jj] = (__bf16)f0[jj]; t[4 + jj] = (__bf16)f1[jj]; }
      af[rt] = t;
    }
#pragma unroll
    for (int ct = 0; ct < 2; ct++)
      bv[ct] = ldg8(Bbase + (size_t)(32 * w4 + 16 * ct + r) * 128 + ks * 32 + q * 8);
#pragma unroll
    for (int rt = 0; rt < 4; rt++)
#pragma unroll
      for (int ct = 0; ct < 2; ct++) MFMA16(acc[rt][ct], af[rt], bv[ct]);
  }
#pragma unroll
  for (int ct = 0; ct < 2; ct++) {
    int n = nt * 128 + 32 * w4 + 16 * ct + r;
    size_t base = ((size_t)b * 4096 + n) * 1024 + g * 64;
#pragma unroll
    for (int rt = 0; rt < 4; rt++) {
      int d0 = 16 * rt + 4 * q;
      u32x2 pk = pack4(acc[rt][ct][0], acc[rt][ct][1], acc[rt][ct][2], acc[rt][ct][3]);
      *(u32x2*)&out1[base + d0] = pk;
    }
  }
}

// ------- fin2: out[16384,1024] = out1 @ WoT^T, mask rows, fp32; grid x=row ------------
__global__ __launch_bounds__(256, 2) void k_fin2(
    const unsigned short* __restrict__ A, const unsigned short* __restrict__ Bt,
    const int* __restrict__ mask, float* __restrict__ out)
{
  __shared__ __align__(16) unsigned short lA[4096];
  __shared__ __align__(16) unsigned short lB[4096];
  const int tid = threadIdx.x, lane = tid & 63, w = tid >> 6;
  const int q = lane >> 4, r = lane & 15, wr = w >> 1, wc = w & 1;
  const int row0 = blockIdx.x * 128, col0 = blockIdx.y * 128;
  const int c1 = w, c2 = w + 4;
  const int sr1 = c1 * 16 + (lane >> 2), sr2 = c2 * 16 + (lane >> 2);
  const int sk = 8 * (lane & 3);
  const unsigned short* gA1 = A + (size_t)(row0 + sr1) * 1024 + sk;
  const unsigned short* gA2 = A + (size_t)(row0 + sr2) * 1024 + sk;
  const unsigned short* gB1 = Bt + (size_t)(col0 + sr1) * 1024 + sk;
  const unsigned short* gB2 = Bt + (size_t)(col0 + sr2) * 1024 + sk;
  f32x4 acc[4][4];
  const f32x4 z = {0.f, 0.f, 0.f, 0.f};
#pragma unroll
  for (int i = 0; i < 4; i++)
#pragma unroll
    for (int j = 0; j < 4; j++) acc[i][j] = z;
  for (int k0 = 0; k0 < 1024; k0 += 32) {
    g2l16(gA1 + k0, &lA[c1 * 512]);
    g2l16(gA2 + k0, &lA[c2 * 512]);
    g2l16(gB1 + k0, &lB[c1 * 512]);
    g2l16(gB2 + k0, &lB[c2 * 512]);
    __syncthreads();
    bf16x8 af[4], bv[4];
#pragma unroll
    for (int rt = 0; rt < 4; rt++) af[rt] = *(const bf16x8*)&lA[(64 * wr + 16 * rt + r) * 32 + q * 8];
#pragma unroll
    for (int ct = 0; ct < 4; ct++) bv[ct] = *(const bf16x8*)&lB[(64 * wc + 16 * ct + r) * 32 + q * 8];
#pragma unroll
    for (int rt = 0; rt < 4; rt++)
#pragma unroll
      for (int ct = 0; ct < 4; ct++) MFMA16(acc[rt][ct], af[rt], bv[ct]);
    __syncthreads();
  }
#pragma unroll
  for (int rt = 0; rt < 4; rt++)
#pragma unroll
    for (int reg = 0; reg < 4; reg++) {
      int row = row0 + 64 * wr + 16 * rt + 4 * q + reg;
      int mv = mask[row];
#pragma unroll
      for (int ct = 0; ct < 4; ct++) {
        int c = col0 + 64 * wc + 16 * ct + r;
        out[(size_t)row * 1024 + c] = mv ? acc[rt][ct][reg] : 0.0f;
      }
    }
}

// =====================================================================================
extern "C" void kernel_launch(void* const* d_in, const int* in_sizes, int n_in,
                              void* d_out, int out_size, void* d_ws, size_t ws_size,
                              hipStream_t stream) {
  const float* x    = (const float*)d_in[0];
  const int*   mask = (const int*)d_in[1];
  const float* Wqkv = (const float*)d_in[2];
  const float* ag   = (const float*)d_in[3];
  const float* Wqa  = (const float*)d_in[4];
  const float* Wak  = (const float*)d_in[5];
  const float* Wout = (const float*)d_in[6];
  float* out = (float*)d_out;
  char* ws = (char*)d_ws;

  // workspace layout, lifetime-overlapped; total 239,370,240 B (same as round 1-3)
  unsigned short* QA    = (unsigned short*)(ws + 0);           // [qk -> mixqa]
  unsigned short* QQ    = (unsigned short*)(ws + 67108864);    // Q [gemm -> qk]
  unsigned short* KK    = (unsigned short*)(ws + 67108864 + 33554432);  // K [gemm -> qk]
  unsigned short* MIX   = QQ;                                  // [mix -> ao] (spans QQ+KK)
  unsigned short* out1  = QQ;                                  // [o1 -> fin2]
  unsigned short* VT    = (unsigned short*)(ws + 134217728);   // Vt [gemm -> ao]
  unsigned short* Xb    = (unsigned short*)(ws + 167772160);   // [prep -> gemm]
  unsigned short* WqkvT = (unsigned short*)(ws + 167772160 + 33554432);
  unsigned short* E     = Xb;                                  // [qk -> mix]
  float*          Ppart = (float*)Xb;                          // 16MB [ao -> aored] (E dead)
  unsigned short* QAmix = Xb;                                  // [mixqa -> o1] (Ppart dead)
  char* sm = ws + 234881024;
  unsigned short* Ab  = (unsigned short*)(sm);                 // 256 KB
  unsigned short* WoT = (unsigned short*)(sm + 262144);        // 2 MB
  float* rowsum = (float*)(sm + 262144 + 2097152);             // 32 KB
  float* AOt    = (float*)(sm + 262144 + 2097152 + 32768);     // 2 MB [b,g,d,m] fp32

  k_prep<<<20616, 256, 0, stream>>>(x, Wqkv, ag, Wout, Xb, WqkvT, Ab, WoT, rowsum);
  k_gemm_qkv<<<dim3(128, 24), 256, 0, stream>>>(Xb, WqkvT, QQ, KK, VT);
  k_qk<<<dim3(32, 16, 4), 256, 0, stream>>>(QQ, KK, Ab, mask, QA, E, rowsum);
  k_mix<<<dim3(4, 128, 4), 256, 0, stream>>>(E, rowsum, Wak, MIX);
  k_ao<<<dim3(8, 16, 4), 256, 0, stream>>>(MIX, VT, Ppart);
  k_aored<<<512, 256, 0, stream>>>(Ppart, AOt);
  k_mixqa<<<dim3(512, 4), 256, 0, stream>>>(QA, Wqa, QAmix);
  k_o1<<<dim3(32, 16, 4), 256, 0, stream>>>(QAmix, AOt, out1);
  k_fin2<<<dim3(128, 8), 256, 0, stream>>>(out1, WoT, mask, out);
}